// Round 4
// baseline (1150.534 us; speedup 1.0000x reference)
//
#include <hip/hip_runtime.h>
#include <hip/hip_bf16.h>
#include <math.h>

typedef __bf16 bf16;
typedef __bf16 bf16x8 __attribute__((ext_vector_type(8)));
typedef float  f32x4  __attribute__((ext_vector_type(4)));

// async global->LDS, 16 B per lane; LDS dest = wave-uniform base + lane*16
__device__ __forceinline__ void load16_lds(const bf16* g, bf16* l) {
    __builtin_amdgcn_global_load_lds(
        (__attribute__((address_space(1))) void*)(g),
        (__attribute__((address_space(3))) void*)(l), 16, 0, 0);
}

// tanh-form GELU (max abs err vs exact erf-GELU ~7e-4)
__device__ __forceinline__ float gelu_f(float x) {
    float u = 1.5957691216057308f * (x + 0.044715f * x * x * x);  // 2*sqrt(2/pi)*(...)
    float e = __expf(u);
    float th = 1.0f - 2.0f / (1.0f + e);
    return 0.5f * x * (1.0f + th);
}

// ---------------- fused weight converts ----------------
struct ConvArgs {
    const float* src[19];
    bf16* dst[19];
    int n[19];
    int bstart[20];
};
__global__ __launch_bounds__(256) void convert_many(ConvArgs a) {
    int blk = blockIdx.x;
    int s = 0;
    while (blk >= a.bstart[s + 1]) s++;
    const float* src = a.src[s];
    bf16* dst = a.dst[s];
    int n = a.n[s];
    int i0 = (blk - a.bstart[s]) * 2048;
#pragma unroll
    for (int e = 0; e < 8; e++) {
        int i = i0 + threadIdx.x + e * 256;
        if (i < n) dst[i] = (bf16)src[i];
    }
}

__global__ void zero_kernel(bf16* dst, int n) {
    int i = blockIdx.x * blockDim.x + threadIdx.x;
    if (i < n) dst[i] = (bf16)0.0f;
}

// ---------------- LayerNorm ----------------
template<class XT>
__global__ __launch_bounds__(256) void ln_kernel(
    const XT* __restrict__ X, const bf16* __restrict__ w,
    const bf16* __restrict__ b, bf16* __restrict__ out)
{
    const int C = 1024;
    const int row = blockIdx.x;
    const int tid = threadIdx.x;
    const XT* xr = X + (size_t)row * C;
    float x0 = (float)xr[tid * 4 + 0], x1 = (float)xr[tid * 4 + 1];
    float x2 = (float)xr[tid * 4 + 2], x3 = (float)xr[tid * 4 + 3];
    float s  = x0 + x1 + x2 + x3;
    float sq = x0*x0 + x1*x1 + x2*x2 + x3*x3;
#pragma unroll
    for (int off = 32; off >= 1; off >>= 1) {
        s  += __shfl_xor(s,  off, 64);
        sq += __shfl_xor(sq, off, 64);
    }
    __shared__ float red[8];
    int wave = tid >> 6;
    if ((tid & 63) == 0) { red[wave] = s; red[4 + wave] = sq; }
    __syncthreads();
    float ts = red[0] + red[1] + red[2] + red[3];
    float tq = red[4] + red[5] + red[6] + red[7];
    float mean = ts * (1.0f / C);
    float var  = tq * (1.0f / C) - mean * mean;
    float rstd = rsqrtf(var + 1e-5f);
    float w0 = (float)w[tid*4+0], w1 = (float)w[tid*4+1], w2 = (float)w[tid*4+2], w3 = (float)w[tid*4+3];
    float b0 = (float)b[tid*4+0], b1 = (float)b[tid*4+1], b2 = (float)b[tid*4+2], b3 = (float)b[tid*4+3];
    bf16* orow = out + (size_t)row * C + tid * 4;
    orow[0] = (bf16)((x0 - mean) * rstd * w0 + b0);
    orow[1] = (bf16)((x1 - mean) * rstd * w1 + b1);
    orow[2] = (bf16)((x2 - mean) * rstd * w2 + b2);
    orow[3] = (bf16)((x3 - mean) * rstd * w3 + b3);
}

// ---------------- GEMM 128x128, 3-buffer 2-deep prefetch, counted vmcnt ----------------
// out = act((A[M,K] @ W[N,K]^T + bias)*scale) + resid
// Main loop NEVER drains vmcnt to 0 (T4): tile t+2's 8 loads stay in flight
// across the barrier; vmcnt(8) confirms tile t+1 (own wave) before s_barrier,
// which makes all waves' t+1 writes LDS-visible after the barrier.
template<int ACT, int OMODE, class RT, class OT>
__global__ __launch_bounds__(256) void gemm_kernel(
    const bf16* __restrict__ A, const bf16* __restrict__ W,
    const bf16* __restrict__ bias, const RT* __restrict__ resid,
    OT* __restrict__ out, bf16* __restrict__ out_k, bf16* __restrict__ out_v,
    int M, int N, int K, float scale, int gmT, int gnT, int mQ)
{
    const int lin = blockIdx.x;
    const int xcd = lin & 7;
    const int t_  = lin >> 3;
    const int mt_ = (xcd & 3) + 4 * (t_ % mQ);
    const int nt_ = (xcd >> 2) + 2 * (t_ / mQ);
    if (mt_ >= gmT || nt_ >= gnT) return;
    const int m0 = mt_ * 128;
    const int n0 = nt_ * 128;

    __shared__ __align__(16) bf16 As[3][16 * 512];   // chunk (msub*2+kk): 1 KB each
    __shared__ __align__(16) bf16 Bs[3][16 * 512];
    const int tid = threadIdx.x;
    const int wave = tid >> 6, lane = tid & 63;
    const int lane15 = lane & 15, quad = lane >> 4;
    const int wm0 = (wave >> 1) * 64;
    const int wn0 = (wave & 1) * 64;
    f32x4 acc[4][4] = {};

    int ra0 = m0 + (2 * wave)     * 16 + lane15; if (ra0 > M - 1) ra0 = M - 1;
    int ra1 = m0 + (2 * wave + 1) * 16 + lane15; if (ra1 > M - 1) ra1 = M - 1;
    const int rb0 = n0 + (2 * wave)     * 16 + lane15;
    const int rb1 = n0 + (2 * wave + 1) * 16 + lane15;
    const bf16* a0 = A + (size_t)ra0 * K + quad * 8;
    const bf16* a1 = A + (size_t)ra1 * K + quad * 8;
    const bf16* w0 = W + (size_t)rb0 * K + quad * 8;
    const bf16* w1 = W + (size_t)rb1 * K + quad * 8;

    auto stage = [&](int buf, int k0) {    // 8 loads per wave
#pragma unroll
        for (int kk = 0; kk < 2; kk++) {
            load16_lds(a0 + k0 + kk * 32, &As[buf][((2 * wave)     * 2 + kk) * 512]);
            load16_lds(a1 + k0 + kk * 32, &As[buf][((2 * wave + 1) * 2 + kk) * 512]);
            load16_lds(w0 + k0 + kk * 32, &Bs[buf][((2 * wave)     * 2 + kk) * 512]);
            load16_lds(w1 + k0 + kk * 32, &Bs[buf][((2 * wave + 1) * 2 + kk) * 512]);
        }
    };

    const int nsteps = K >> 6;
    // prologue: stage tiles 0 and 1; confirm tile 0 (vmcnt(8): tile 1 stays in flight)
    stage(0, 0);
    if (nsteps > 1) {
        stage(1, 64);
        asm volatile("s_waitcnt vmcnt(8)" ::: "memory");
    } else {
        asm volatile("s_waitcnt vmcnt(0)" ::: "memory");
    }
    __builtin_amdgcn_s_barrier();
    __builtin_amdgcn_sched_barrier(0);

    for (int t = 0; t < nsteps; t++) {
        const int cur = t % 3;
        if (t + 2 < nsteps) {
            stage((t + 2) % 3, (t + 2) << 6);   // depth-2 prefetch
            __builtin_amdgcn_sched_barrier(0);  // pin issue before compute/wait
        }
#pragma unroll
        for (int kk = 0; kk < 2; kk++) {
            bf16x8 af[4], bfr[4];
#pragma unroll
            for (int tt = 0; tt < 4; tt++) {
                af[tt]  = *(const bf16x8*)(&As[cur][(((wm0 >> 4) + tt) * 2 + kk) * 512 + lane * 8]);
                bfr[tt] = *(const bf16x8*)(&Bs[cur][(((wn0 >> 4) + tt) * 2 + kk) * 512 + lane * 8]);
            }
#pragma unroll
            for (int mt = 0; mt < 4; mt++)
#pragma unroll
                for (int nt = 0; nt < 4; nt++)
                    acc[mt][nt] = __builtin_amdgcn_mfma_f32_16x16x32_bf16(
                        af[mt], bfr[nt], acc[mt][nt], 0, 0, 0);
        }
        if (t + 1 < nsteps) {
            // confirm tile t+1 (oldest 8); tile t+2's loads stay in flight
            if (t + 2 < nsteps) asm volatile("s_waitcnt vmcnt(8)" ::: "memory");
            else                asm volatile("s_waitcnt vmcnt(0)" ::: "memory");
            __builtin_amdgcn_s_barrier();
            __builtin_amdgcn_sched_barrier(0);
        }
    }

    // epilogue: C/D layout col=lane&15, row=quad*4+reg
#pragma unroll
    for (int mt = 0; mt < 4; mt++) {
#pragma unroll
        for (int r = 0; r < 4; r++) {
            int gm = m0 + wm0 + mt * 16 + quad * 4 + r;
            if (gm >= M) continue;
#pragma unroll
            for (int nt = 0; nt < 4; nt++) {
                int gn = n0 + wn0 + nt * 16 + lane15;
                float v = acc[mt][nt][r];
                if (bias) v += (float)bias[gn];
                if (OMODE == 2) {
                    if (gn < 2048) {
                        v *= scale;
                        if (gn < 1024) v *= 1.4426950408889634f;  // exp2-domain softmax
                    }
                } else v *= scale;
                if (ACT == 1) v = gelu_f(v);
                if (OMODE == 2) {
                    if (gn < 1024) {
                        ((bf16*)out)[(size_t)gm * 1024 + gn] = (bf16)v;            // q
                    } else if (gn < 2048) {
                        out_k[(size_t)gm * 1024 + (gn - 1024)] = (bf16)v;          // k
                    } else {
                        int gg = gn - 2048;
                        int bb = gm / 1500;
                        int ss = gm - bb * 1500;
                        int hh = gg >> 6, dd = gg & 63;
                        out_v[(((size_t)bb * 16 + hh) * 64 + dd) * 1536 + ss] = (bf16)v;  // v^T
                    }
                } else {
                    if (resid) v += (float)resid[(size_t)gm * N + gn];
                    out[(size_t)gm * N + gn] = (OT)v;
                }
            }
        }
    }
}

// ---------------- Flash attention (2-phase double-buffered K/V) ----------------
__global__ __launch_bounds__(256) void flash_attn_kernel(
    const bf16* __restrict__ Q, const bf16* __restrict__ Km,
    const bf16* __restrict__ Vt, bf16* __restrict__ O)
{
    const int S = 1500, C = 1024, SP = 1536;
    const int LDP = 72;
    __shared__ __align__(16) bf16 Ks[2][8 * 512];
    __shared__ __align__(16) bf16 Vs[2][8 * 512];
    __shared__ __align__(16) bf16 Ps[4 * 16 * LDP];
    const int tid = threadIdx.x;
    const int wave = tid >> 6, lane = tid & 63;
    const int lane15 = lane & 15, quad = lane >> 4;
    const int bh = blockIdx.y;
    const int q0 = blockIdx.x * 64;
    const size_t headoff = (size_t)(bh >> 4) * S * C + (size_t)(bh & 15) * 64;
    const size_t vtoff   = (size_t)bh * 64 * SP;

    bf16x8 qf[2];
    int qr = q0 + wave * 16 + lane15; if (qr > S - 1) qr = S - 1;
    qf[0] = *(const bf16x8*)(Q + headoff + (size_t)qr * C + quad * 8);
    qf[1] = *(const bf16x8*)(Q + headoff + (size_t)qr * C + 32 + quad * 8);

    const bf16* vbase = Vt + vtoff + (size_t)(wave * 16 + lane15) * SP + quad * 8;

    auto stageKV = [&](int buf, int kt) {
        const int j0 = kt * 64;
        int kr = j0 + wave * 16 + lane15; if (kr > S - 1) kr = S - 1;
        const bf16* kbase = Km + headoff + (size_t)kr * C + quad * 8;
#pragma unroll
        for (int kk = 0; kk < 2; kk++) {
            load16_lds(kbase + kk * 32,      &Ks[buf][(wave * 2 + kk) * 512]);
            load16_lds(vbase + j0 + kk * 32, &Vs[buf][(wave * 2 + kk) * 512]);
        }
    };

    float m_run[4], l_part[4];
    f32x4 o_acc[4] = {};
#pragma unroll
    for (int r = 0; r < 4; r++) { m_run[r] = 4.0f; l_part[r] = 0.0f; }

    stageKV(0, 0);
    asm volatile("s_waitcnt vmcnt(0)" ::: "memory");
    __builtin_amdgcn_s_barrier();
    __builtin_amdgcn_sched_barrier(0);

    int cur = 0;
    for (int kt = 0; kt < 24; kt++) {
        if (kt + 1 < 24) stageKV(cur ^ 1, kt + 1);
        const int j0 = kt * 64;

        f32x4 s[4] = {};
#pragma unroll
        for (int kk = 0; kk < 2; kk++) {
#pragma unroll
            for (int nt = 0; nt < 4; nt++) {
                bf16x8 kf = *(const bf16x8*)(&Ks[cur][(nt * 2 + kk) * 512 + lane * 8]);
                s[nt] = __builtin_amdgcn_mfma_f32_16x16x32_bf16(qf[kk], kf, s[nt], 0, 0, 0);
            }
        }
        if (kt == 23) {
#pragma unroll
            for (int nt = 0; nt < 4; nt++) {
                if (j0 + nt * 16 + lane15 >= S) {
#pragma unroll
                    for (int r = 0; r < 4; r++) s[nt][r] = -1e30f;
                }
            }
        }

        float tm[4];
#pragma unroll
        for (int r = 0; r < 4; r++)
            tm[r] = fmaxf(fmaxf(s[0][r], s[1][r]), fmaxf(s[2][r], s[3][r]));
        bool rec = (tm[0] > m_run[0]) | (tm[1] > m_run[1]) |
                   (tm[2] > m_run[2]) | (tm[3] > m_run[3]);
        if (__any(rec)) {
#pragma unroll
            for (int r = 0; r < 4; r++) {
                float rm = tm[r];
#pragma unroll
                for (int off = 1; off < 16; off <<= 1) rm = fmaxf(rm, __shfl_xor(rm, off, 64));
                float mnew  = fmaxf(m_run[r], rm);
                float alpha = __builtin_amdgcn_exp2f(m_run[r] - mnew);
                m_run[r] = mnew;
                l_part[r] *= alpha;
#pragma unroll
                for (int dt = 0; dt < 4; dt++) o_acc[dt][r] *= alpha;
            }
        }

#pragma unroll
        for (int nt = 0; nt < 4; nt++) {
#pragma unroll
            for (int r = 0; r < 4; r++) {
                float p = __builtin_amdgcn_exp2f(s[nt][r] - m_run[r]);
                l_part[r] += p;
                Ps[wave * 16 * LDP + (quad * 4 + r) * LDP + nt * 16 + lane15] = (bf16)p;
            }
        }
        asm volatile("s_waitcnt lgkmcnt(0)" ::: "memory");
        __builtin_amdgcn_sched_barrier(0);
#pragma unroll
        for (int kk = 0; kk < 2; kk++) {
            bf16x8 pf = *(const bf16x8*)(&Ps[wave * 16 * LDP + lane15 * LDP + kk * 32 + quad * 8]);
#pragma unroll
            for (int dt = 0; dt < 4; dt++) {
                bf16x8 vf = *(const bf16x8*)(&Vs[cur][(dt * 2 + kk) * 512 + lane * 8]);
                o_acc[dt] = __builtin_amdgcn_mfma_f32_16x16x32_bf16(pf, vf, o_acc[dt], 0, 0, 0);
            }
        }
        if (kt + 1 < 24) {
            asm volatile("s_waitcnt vmcnt(0)" ::: "memory");
            __builtin_amdgcn_s_barrier();
            __builtin_amdgcn_sched_barrier(0);
        }
        cur ^= 1;
    }

    float l_inv[4];
#pragma unroll
    for (int r = 0; r < 4; r++) {
        float ls = l_part[r];
#pragma unroll
        for (int off = 1; off < 16; off <<= 1) ls += __shfl_xor(ls, off, 64);
        l_inv[r] = 1.0f / ls;
    }

#pragma unroll
    for (int dt = 0; dt < 4; dt++) {
#pragma unroll
        for (int r = 0; r < 4; r++) {
            int row = q0 + wave * 16 + quad * 4 + r;
            if (row < S) {
                float v = o_acc[dt][r] * l_inv[r];
                O[headoff + (size_t)row * C + dt * 16 + lane15] = (bf16)v;
            }
        }
    }
}

extern "C" void kernel_launch(void* const* d_in, const int* in_sizes, int n_in,
                              void* d_out, int out_size, void* d_ws, size_t ws_size,
                              hipStream_t stream) {
    float* out = (float*)d_out;
    const float* x_f32 = (const float*)d_in[0];
    const int M = 6000, Cc = 1024, F = 4096, Aa = 256;
    const size_t MC = (size_t)M * Cc;
    const size_t VT_ELEMS = (size_t)64 * 64 * 1536;
    bf16* ws = (bf16*)d_ws;

    bf16* h1   = ws;                         // [M,C]
    bf16* kbuf = ws + MC;                    // [M,C]
    bf16* Vt   = ws + 2 * MC;                // [64][64][1536]
    bf16* g    = ws + 2 * MC + VT_ELEMS;     // [M,F]
    bf16* q    = (bf16*)d_out;               // d_out spare half as bf16 scratch
    bf16* wv   = h1;
    bf16* x1   = q;
    bf16* h2   = kbuf;
    bf16* x2   = Vt;
    bf16* aact = kbuf;

    size_t off = 2 * MC + VT_ELEMS + (size_t)M * F;
    bf16* Wqkv = ws + off; off += (size_t)3 * 1024 * 1024;
    bf16* bqkv = ws + off; off += 3072;
    bf16* sWo  = ws + off; off += (size_t)1024 * 1024;
    bf16* sbo  = ws + off; off += 1024;
    bf16* slnw = ws + off; off += 1024;
    bf16* slnb = ws + off; off += 1024;
    bf16* sW1  = ws + off; off += (size_t)4096 * 1024;
    bf16* sb1  = ws + off; off += 4096;
    bf16* sW2  = ws + off; off += (size_t)1024 * 4096;
    bf16* sb2  = ws + off; off += 1024;
    bf16* sln2w = ws + off; off += 1024;
    bf16* sln2b = ws + off; off += 1024;
    bf16* sWds = ws + off; off += (size_t)256 * 1024;
    bf16* sbds = ws + off; off += 256;
    bf16* sWus = ws + off; off += (size_t)1024 * 256;
    bf16* sbus = ws + off; off += 1024;

    ConvArgs ca;
    const int srcidx[19] = {1, 3, 4, 2, 5, 6, 7, 8, 9, 10, 11, 12, 13, 14, 15, 16, 17, 18, 19};
    bf16* dsts[19] = {Wqkv, Wqkv + 1048576, Wqkv + 2097152, bqkv, bqkv + 2048,
                      sWo, sbo, slnw, slnb, sW1, sb1, sW2, sb2, sln2w, sln2b,
                      sWds, sbds, sWus, sbus};
    int bacc = 0;
    for (int i = 0; i < 19; i++) {
        ca.src[i] = (const float*)d_in[srcidx[i]];
        ca.dst[i] = dsts[i];
        ca.n[i] = in_sizes[srcidx[i]];
        ca.bstart[i] = bacc;
        bacc += (ca.n[i] + 2047) / 2048;
    }
    ca.bstart[19] = bacc;

    dim3 blk(256);
    convert_many<<<bacc, blk, 0, stream>>>(ca);
    zero_kernel<<<4, blk, 0, stream>>>(bqkv + 1024, 1024);   // no k-bias

    const float scale = 0.35355339059327373f;  // 64^-0.25
    const int gmT = 47, mQ = 12;               // ceil(47/4)
    auto grid_for = [&](int gnT) { int nQ = (gnT + 1) >> 1; return dim3(8 * mQ * nQ); };

    ln_kernel<float><<<M, blk, 0, stream>>>(x_f32, slnw, slnb, h1);
    gemm_kernel<0, 2, bf16, bf16><<<grid_for(24), blk, 0, stream>>>(
        h1, Wqkv, bqkv, (const bf16*)nullptr, q, kbuf, Vt, M, 3072, Cc, scale, gmT, 24, mQ);
    dim3 ga(24, 64);
    flash_attn_kernel<<<ga, blk, 0, stream>>>(q, kbuf, Vt, wv);
    gemm_kernel<0, 0, float, bf16><<<grid_for(8), blk, 0, stream>>>(
        wv, sWo, sbo, x_f32, x1, nullptr, nullptr, M, Cc, Cc, 1.0f, gmT, 8, mQ);
    ln_kernel<bf16><<<M, blk, 0, stream>>>(x1, sln2w, sln2b, h2);
    gemm_kernel<1, 0, bf16, bf16><<<grid_for(32), blk, 0, stream>>>(
        h2, sW1, sb1, (const bf16*)nullptr, g, nullptr, nullptr, M, F, Cc, 1.0f, gmT, 32, mQ);
    gemm_kernel<0, 0, bf16, bf16><<<grid_for(8), blk, 0, stream>>>(
        g, sW2, sb2, x1, x2, nullptr, nullptr, M, Cc, F, 1.0f, gmT, 8, mQ);
    gemm_kernel<1, 0, bf16, bf16><<<grid_for(2), blk, 0, stream>>>(
        x2, sWds, sbds, (const bf16*)nullptr, aact, nullptr, nullptr, M, Aa, Cc, 1.0f, gmT, 2, mQ);
    gemm_kernel<0, 0, bf16, float><<<grid_for(8), blk, 0, stream>>>(
        aact, sWus, sbus, x2, out, nullptr, nullptr, M, Cc, Aa, 1.0f, gmT, 8, mQ);
}

// Round 5
// 851.990 us; speedup vs baseline: 1.3504x; 1.3504x over previous
//
#include <hip/hip_runtime.h>
#include <hip/hip_bf16.h>
#include <math.h>

typedef __bf16 bf16;
typedef __bf16 bf16x8 __attribute__((ext_vector_type(8)));
typedef float  f32x4  __attribute__((ext_vector_type(4)));

// async global->LDS, 16 B per lane; LDS dest = wave-uniform base + lane*16
__device__ __forceinline__ void load16_lds(const bf16* g, bf16* l) {
    __builtin_amdgcn_global_load_lds(
        (__attribute__((address_space(1))) void*)(g),
        (__attribute__((address_space(3))) void*)(l), 16, 0, 0);
}

// tanh-form GELU (max abs err vs exact erf-GELU ~7e-4)
__device__ __forceinline__ float gelu_f(float x) {
    float u = 1.5957691216057308f * (x + 0.044715f * x * x * x);  // 2*sqrt(2/pi)*(...)
    float e = __expf(u);
    float th = 1.0f - 2.0f / (1.0f + e);
    return 0.5f * x * (1.0f + th);
}

// shared epilogue
template<int ACT, int OMODE, class RT, class OT>
__device__ __forceinline__ void gemm_epilogue_elem(
    float v, int gm, int gn, int M, int N, float scale,
    const bf16* __restrict__ bias, const RT* __restrict__ resid,
    OT* __restrict__ out, bf16* __restrict__ out_k, bf16* __restrict__ out_v)
{
    if (bias) v += (float)bias[gn];
    if (OMODE == 2) {
        if (gn < 2048) {
            v *= scale;
            if (gn < 1024) v *= 1.4426950408889634f;  // exp2-domain softmax
        }
    } else v *= scale;
    if (ACT == 1) v = gelu_f(v);
    if (OMODE == 2) {
        if (gn < 1024) {
            ((bf16*)out)[(size_t)gm * 1024 + gn] = (bf16)v;            // q
        } else if (gn < 2048) {
            out_k[(size_t)gm * 1024 + (gn - 1024)] = (bf16)v;          // k
        } else {
            int gg = gn - 2048;
            int bb = gm / 1500;
            int ss = gm - bb * 1500;
            int hh = gg >> 6, dd = gg & 63;
            out_v[(((size_t)bb * 16 + hh) * 64 + dd) * 1536 + ss] = (bf16)v;  // v^T
        }
    } else {
        if (resid) v += (float)resid[(size_t)gm * N + gn];
        out[(size_t)gm * N + gn] = (OT)v;
    }
}

// ---------------- fused weight converts ----------------
struct ConvArgs {
    const float* src[19];
    bf16* dst[19];
    int n[19];
    int bstart[20];
};
__global__ __launch_bounds__(256) void convert_many(ConvArgs a) {
    int blk = blockIdx.x;
    int s = 0;
    while (blk >= a.bstart[s + 1]) s++;
    const float* src = a.src[s];
    bf16* dst = a.dst[s];
    int n = a.n[s];
    int i0 = (blk - a.bstart[s]) * 2048;
#pragma unroll
    for (int e = 0; e < 8; e++) {
        int i = i0 + threadIdx.x + e * 256;
        if (i < n) dst[i] = (bf16)src[i];
    }
}

__global__ void zero_kernel(bf16* dst, int n) {
    int i = blockIdx.x * blockDim.x + threadIdx.x;
    if (i < n) dst[i] = (bf16)0.0f;
}

// ---------------- LayerNorm ----------------
template<class XT>
__global__ __launch_bounds__(256) void ln_kernel(
    const XT* __restrict__ X, const bf16* __restrict__ w,
    const bf16* __restrict__ b, bf16* __restrict__ out)
{
    const int C = 1024;
    const int row = blockIdx.x;
    const int tid = threadIdx.x;
    const XT* xr = X + (size_t)row * C;
    float x0 = (float)xr[tid * 4 + 0], x1 = (float)xr[tid * 4 + 1];
    float x2 = (float)xr[tid * 4 + 2], x3 = (float)xr[tid * 4 + 3];
    float s  = x0 + x1 + x2 + x3;
    float sq = x0*x0 + x1*x1 + x2*x2 + x3*x3;
#pragma unroll
    for (int off = 32; off >= 1; off >>= 1) {
        s  += __shfl_xor(s,  off, 64);
        sq += __shfl_xor(sq, off, 64);
    }
    __shared__ float red[8];
    int wave = tid >> 6;
    if ((tid & 63) == 0) { red[wave] = s; red[4 + wave] = sq; }
    __syncthreads();
    float ts = red[0] + red[1] + red[2] + red[3];
    float tq = red[4] + red[5] + red[6] + red[7];
    float mean = ts * (1.0f / C);
    float var  = tq * (1.0f / C) - mean * mean;
    float rstd = rsqrtf(var + 1e-5f);
    float w0 = (float)w[tid*4+0], w1 = (float)w[tid*4+1], w2 = (float)w[tid*4+2], w3 = (float)w[tid*4+3];
    float b0 = (float)b[tid*4+0], b1 = (float)b[tid*4+1], b2 = (float)b[tid*4+2], b3 = (float)b[tid*4+3];
    bf16* orow = out + (size_t)row * C + tid * 4;
    orow[0] = (bf16)((x0 - mean) * rstd * w0 + b0);
    orow[1] = (bf16)((x1 - mean) * rstd * w1 + b1);
    orow[2] = (bf16)((x2 - mean) * rstd * w2 + b2);
    orow[3] = (bf16)((x3 - mean) * rstd * w3 + b3);
}

// ---------------- GEMM 128x128 (r1-exact: single buffer, 2 barriers/K-step) ----------------
template<int ACT, int OMODE, class RT, class OT>
__global__ __launch_bounds__(256) void gemm_kernel(
    const bf16* __restrict__ A, const bf16* __restrict__ W,
    const bf16* __restrict__ bias, const RT* __restrict__ resid,
    OT* __restrict__ out, bf16* __restrict__ out_k, bf16* __restrict__ out_v,
    int M, int N, int K, float scale, int gmT, int gnT, int mQ)
{
    const int lin = blockIdx.x;
    const int xcd = lin & 7;
    const int t_  = lin >> 3;
    const int mt_ = (xcd & 3) + 4 * (t_ % mQ);
    const int nt_ = (xcd >> 2) + 2 * (t_ / mQ);
    if (mt_ >= gmT || nt_ >= gnT) return;
    const int m0 = mt_ * 128;
    const int n0 = nt_ * 128;

    __shared__ __align__(16) bf16 As[16 * 512];   // chunk (msub*2+kk): 1 KB each
    __shared__ __align__(16) bf16 Bs[16 * 512];
    const int tid = threadIdx.x;
    const int wave = tid >> 6, lane = tid & 63;
    const int lane15 = lane & 15, quad = lane >> 4;
    const int wm0 = (wave >> 1) * 64;
    const int wn0 = (wave & 1) * 64;
    f32x4 acc[4][4] = {};

    int ra0 = m0 + (2 * wave)     * 16 + lane15; if (ra0 > M - 1) ra0 = M - 1;
    int ra1 = m0 + (2 * wave + 1) * 16 + lane15; if (ra1 > M - 1) ra1 = M - 1;
    const int rb0 = n0 + (2 * wave)     * 16 + lane15;
    const int rb1 = n0 + (2 * wave + 1) * 16 + lane15;
    const bf16* a0 = A + (size_t)ra0 * K + quad * 8;
    const bf16* a1 = A + (size_t)ra1 * K + quad * 8;
    const bf16* w0 = W + (size_t)rb0 * K + quad * 8;
    const bf16* w1 = W + (size_t)rb1 * K + quad * 8;

    for (int k0 = 0; k0 < K; k0 += 64) {
#pragma unroll
        for (int kk = 0; kk < 2; kk++) {
            load16_lds(a0 + k0 + kk * 32, &As[((2 * wave)     * 2 + kk) * 512]);
            load16_lds(a1 + k0 + kk * 32, &As[((2 * wave + 1) * 2 + kk) * 512]);
            load16_lds(w0 + k0 + kk * 32, &Bs[((2 * wave)     * 2 + kk) * 512]);
            load16_lds(w1 + k0 + kk * 32, &Bs[((2 * wave + 1) * 2 + kk) * 512]);
        }
        __syncthreads();
#pragma unroll
        for (int kk = 0; kk < 2; kk++) {
            bf16x8 af[4], bfr[4];
#pragma unroll
            for (int tt = 0; tt < 4; tt++) {
                af[tt]  = *(const bf16x8*)(&As[(((wm0 >> 4) + tt) * 2 + kk) * 512 + lane * 8]);
                bfr[tt] = *(const bf16x8*)(&Bs[(((wn0 >> 4) + tt) * 2 + kk) * 512 + lane * 8]);
            }
#pragma unroll
            for (int mt = 0; mt < 4; mt++)
#pragma unroll
                for (int nt = 0; nt < 4; nt++)
                    acc[mt][nt] = __builtin_amdgcn_mfma_f32_16x16x32_bf16(
                        af[mt], bfr[nt], acc[mt][nt], 0, 0, 0);
        }
        __syncthreads();
    }

#pragma unroll
    for (int mt = 0; mt < 4; mt++) {
#pragma unroll
        for (int r = 0; r < 4; r++) {
            int gm = m0 + wm0 + mt * 16 + quad * 4 + r;
            if (gm >= M) continue;
#pragma unroll
            for (int nt = 0; nt < 4; nt++) {
                int gn = n0 + wn0 + nt * 16 + lane15;
                gemm_epilogue_elem<ACT, OMODE, RT, OT>(
                    acc[mt][nt][r], gm, gn, M, N, scale, bias, resid, out, out_k, out_v);
            }
        }
    }
}

// ---------------- GEMM 256x256, 8 waves, 4-phase interleaved K-loop (T3/T4/T5) ----------------
// Wave-tile 128x64 (2M x 4N wave grid). BK=64, dbuf LDS = 128 KB (1 block/CU).
// Per K-tile: 4 phases = (kk, n-half) quadrants of 16 MFMA each. Tile t+1's A is
// staged in phase 0, B in phase 1; the vmcnt(0) for them happens at end of phase 3
// (>= 2 phases of MFMA cover). Fragment-major LDS chunks are bank-conflict-free
// (measured 0 conflicts), so no swizzle is needed. Per-phase s_barrier creates the
// cross-wave stage/read/MFMA interleave (T3); setprio(1) wraps MFMA clusters (T5).
template<int ACT, int OMODE, class RT, class OT>
__global__ __launch_bounds__(512, 2) void gemm256_kernel(
    const bf16* __restrict__ A, const bf16* __restrict__ W,
    const bf16* __restrict__ bias, const RT* __restrict__ resid,
    OT* __restrict__ out, bf16* __restrict__ out_k, bf16* __restrict__ out_v,
    int M, int N, int K, float scale, int gmT, int gnT, int mQ)
{
    const int lin = blockIdx.x;
    const int xcd = lin & 7;
    const int t_  = lin >> 3;
    const int mt_ = (xcd & 3) + 4 * (t_ % mQ);
    const int nt_ = (xcd >> 2) + 2 * (t_ / mQ);
    if (mt_ >= gmT || nt_ >= gnT) return;
    const int m0 = mt_ * 256;
    const int n0 = nt_ * 256;

    __shared__ __align__(16) bf16 As[2][32 * 512];   // 16 row-groups x 2 kk per buf
    __shared__ __align__(16) bf16 Bs[2][32 * 512];
    const int tid = threadIdx.x;
    const int wave = tid >> 6, lane = tid & 63;
    const int lane15 = lane & 15, quad = lane >> 4;
    const int wm0 = (wave >> 2) * 128;   // 2 wave-rows
    const int wn0 = (wave & 3) * 64;     // 4 wave-cols
    f32x4 acc[8][4] = {};

    int ra0 = m0 + (2 * wave)     * 16 + lane15; if (ra0 > M - 1) ra0 = M - 1;
    int ra1 = m0 + (2 * wave + 1) * 16 + lane15; if (ra1 > M - 1) ra1 = M - 1;
    const int rb0 = n0 + (2 * wave)     * 16 + lane15;
    const int rb1 = n0 + (2 * wave + 1) * 16 + lane15;
    const bf16* a0 = A + (size_t)ra0 * K + quad * 8;
    const bf16* a1 = A + (size_t)ra1 * K + quad * 8;
    const bf16* w0 = W + (size_t)rb0 * K + quad * 8;
    const bf16* w1 = W + (size_t)rb1 * K + quad * 8;

    auto stageA = [&](int buf, int k0) {   // 4 gload_lds per wave
#pragma unroll
        for (int kk = 0; kk < 2; kk++) {
            load16_lds(a0 + k0 + kk * 32, &As[buf][((2 * wave)     * 2 + kk) * 512]);
            load16_lds(a1 + k0 + kk * 32, &As[buf][((2 * wave + 1) * 2 + kk) * 512]);
        }
    };
    auto stageB = [&](int buf, int k0) {
#pragma unroll
        for (int kk = 0; kk < 2; kk++) {
            load16_lds(w0 + k0 + kk * 32, &Bs[buf][((2 * wave)     * 2 + kk) * 512]);
            load16_lds(w1 + k0 + kk * 32, &Bs[buf][((2 * wave + 1) * 2 + kk) * 512]);
        }
    };
    auto LDA = [&](int buf, int i, int kk) -> bf16x8 {
        return *(const bf16x8*)(&As[buf][(((wm0 >> 4) + i) * 2 + kk) * 512 + lane * 8]);
    };
    auto LDB = [&](int buf, int j, int kk) -> bf16x8 {
        return *(const bf16x8*)(&Bs[buf][(((wn0 >> 4) + j) * 2 + kk) * 512 + lane * 8]);
    };

    // prologue: stage tile 0 fully
    stageA(0, 0); stageB(0, 0);
    asm volatile("s_waitcnt vmcnt(0)" ::: "memory");
    __builtin_amdgcn_s_barrier();
    __builtin_amdgcn_sched_barrier(0);

    const int nsteps = K >> 6;
    for (int t = 0; t < nsteps; t++) {
        const int cur = t & 1, nxt = cur ^ 1;
        const bool pf = (t + 1 < nsteps);
        const int k1 = (t + 1) << 6;
        bf16x8 af[8], bfr[2];

        // ---- phase 0: kk=0, n-half 0; stage A(t+1)
#pragma unroll
        for (int i = 0; i < 8; i++) af[i] = LDA(cur, i, 0);
        bfr[0] = LDB(cur, 0, 0); bfr[1] = LDB(cur, 1, 0);
        if (pf) stageA(nxt, k1);
        asm volatile("s_waitcnt lgkmcnt(0)" ::: "memory");
        __builtin_amdgcn_sched_barrier(0);
        __builtin_amdgcn_s_setprio(1);
#pragma unroll
        for (int mt = 0; mt < 8; mt++)
#pragma unroll
            for (int j = 0; j < 2; j++)
                acc[mt][j] = __builtin_amdgcn_mfma_f32_16x16x32_bf16(af[mt], bfr[j], acc[mt][j], 0, 0, 0);
        __builtin_amdgcn_s_setprio(0);
        __builtin_amdgcn_s_barrier();

        // ---- phase 1: kk=0, n-half 1; stage B(t+1)
        bfr[0] = LDB(cur, 2, 0); bfr[1] = LDB(cur, 3, 0);
        if (pf) stageB(nxt, k1);
        asm volatile("s_waitcnt lgkmcnt(0)" ::: "memory");
        __builtin_amdgcn_sched_barrier(0);
        __builtin_amdgcn_s_setprio(1);
#pragma unroll
        for (int mt = 0; mt < 8; mt++)
#pragma unroll
            for (int j = 0; j < 2; j++)
                acc[mt][2 + j] = __builtin_amdgcn_mfma_f32_16x16x32_bf16(af[mt], bfr[j], acc[mt][2 + j], 0, 0, 0);
        __builtin_amdgcn_s_setprio(0);
        __builtin_amdgcn_s_barrier();

        // ---- phase 2: kk=1, n-half 0
#pragma unroll
        for (int i = 0; i < 8; i++) af[i] = LDA(cur, i, 1);
        bfr[0] = LDB(cur, 0, 1); bfr[1] = LDB(cur, 1, 1);
        asm volatile("s_waitcnt lgkmcnt(0)" ::: "memory");
        __builtin_amdgcn_sched_barrier(0);
        __builtin_amdgcn_s_setprio(1);
#pragma unroll
        for (int mt = 0; mt < 8; mt++)
#pragma unroll
            for (int j = 0; j < 2; j++)
                acc[mt][j] = __builtin_amdgcn_mfma_f32_16x16x32_bf16(af[mt], bfr[j], acc[mt][j], 0, 0, 0);
        __builtin_amdgcn_s_setprio(0);
        __builtin_amdgcn_s_barrier();

        // ---- phase 3: kk=1, n-half 1; confirm tile t+1 landed
        bfr[0] = LDB(cur, 2, 1); bfr[1] = LDB(cur, 3, 1);
        asm volatile("s_waitcnt lgkmcnt(0)" ::: "memory");
        __builtin_amdgcn_sched_barrier(0);
        __builtin_amdgcn_s_setprio(1);
#pragma unroll
        for (int mt = 0; mt < 8; mt++)
#pragma unroll
            for (int j = 0; j < 2; j++)
                acc[mt][2 + j] = __builtin_amdgcn_mfma_f32_16x16x32_bf16(af[mt], bfr[j], acc[mt][2 + j], 0, 0, 0);
        __builtin_amdgcn_s_setprio(0);
        if (pf) asm volatile("s_waitcnt vmcnt(0)" ::: "memory");
        __builtin_amdgcn_s_barrier();
        __builtin_amdgcn_sched_barrier(0);
    }

#pragma unroll
    for (int mt = 0; mt < 8; mt++) {
#pragma unroll
        for (int r = 0; r < 4; r++) {
            int gm = m0 + wm0 + mt * 16 + quad * 4 + r;
            if (gm >= M) continue;
#pragma unroll
            for (int nt = 0; nt < 4; nt++) {
                int gn = n0 + wn0 + nt * 16 + lane15;
                gemm_epilogue_elem<ACT, OMODE, RT, OT>(
                    acc[mt][nt][r], gm, gn, M, N, scale, bias, resid, out, out_k, out_v);
            }
        }
    }
}

// ---------------- Flash attention (2-phase double-buffered K/V) ----------------
__global__ __launch_bounds__(256) void flash_attn_kernel(
    const bf16* __restrict__ Q, const bf16* __restrict__ Km,
    const bf16* __restrict__ Vt, bf16* __restrict__ O)
{
    const int S = 1500, C = 1024, SP = 1536;
    const int LDP = 72;
    __shared__ __align__(16) bf16 Ks[2][8 * 512];
    __shared__ __align__(16) bf16 Vs[2][8 * 512];
    __shared__ __align__(16) bf16 Ps[4 * 16 * LDP];
    const int tid = threadIdx.x;
    const int wave = tid >> 6, lane = tid & 63;
    const int lane15 = lane & 15, quad = lane >> 4;
    const int bh = blockIdx.y;
    const int q0 = blockIdx.x * 64;
    const size_t headoff = (size_t)(bh >> 4) * S * C + (size_t)(bh & 15) * 64;
    const size_t vtoff   = (size_t)bh * 64 * SP;

    bf16x8 qf[2];
    int qr = q0 + wave * 16 + lane15; if (qr > S - 1) qr = S - 1;
    qf[0] = *(const bf16x8*)(Q + headoff + (size_t)qr * C + quad * 8);
    qf[1] = *(const bf16x8*)(Q + headoff + (size_t)qr * C + 32 + quad * 8);

    const bf16* vbase = Vt + vtoff + (size_t)(wave * 16 + lane15) * SP + quad * 8;

    auto stageKV = [&](int buf, int kt) {
        const int j0 = kt * 64;
        int kr = j0 + wave * 16 + lane15; if (kr > S - 1) kr = S - 1;
        const bf16* kbase = Km + headoff + (size_t)kr * C + quad * 8;
#pragma unroll
        for (int kk = 0; kk < 2; kk++) {
            load16_lds(kbase + kk * 32,      &Ks[buf][(wave * 2 + kk) * 512]);
            load16_lds(vbase + j0 + kk * 32, &Vs[buf][(wave * 2 + kk) * 512]);
        }
    };

    float m_run[4], l_part[4];
    f32x4 o_acc[4] = {};
#pragma unroll
    for (int r = 0; r < 4; r++) { m_run[r] = 4.0f; l_part[r] = 0.0f; }

    stageKV(0, 0);
    asm volatile("s_waitcnt vmcnt(0)" ::: "memory");
    __builtin_amdgcn_s_barrier();
    __builtin_amdgcn_sched_barrier(0);

    int cur = 0;
    for (int kt = 0; kt < 24; kt++) {
        if (kt + 1 < 24) stageKV(cur ^ 1, kt + 1);
        const int j0 = kt * 64;

        f32x4 s[4] = {};
#pragma unroll
        for (int kk = 0; kk < 2; kk++) {
#pragma unroll
            for (int nt = 0; nt < 4; nt++) {
                bf16x8 kf = *(const bf16x8*)(&Ks[cur][(nt * 2 + kk) * 512 + lane * 8]);
                s[nt] = __builtin_amdgcn_mfma_f32_16x16x32_bf16(qf[kk], kf, s[nt], 0, 0, 0);
            }
        }
        if (kt == 23) {
#pragma unroll
            for (int nt = 0; nt < 4; nt++) {
                if (j0 + nt * 16 + lane15 >= S) {
#pragma unroll
                    for (int r = 0; r < 4; r++) s[nt][r] = -1e30f;
                }
            }
        }

        float tm[4];
#pragma unroll
        for (int r = 0; r < 4; r++)
            tm[r] = fmaxf(fmaxf(s[0][r], s[1][r]), fmaxf(s[2][r], s[3][r]));
        bool rec = (tm[0] > m_run[0]) | (tm[1] > m_run[1]) |
                   (tm[2] > m_run[2]) | (tm[3] > m_run[3]);
        if (__any(rec)) {
#pragma unroll
            for (int r = 0; r < 4; r++) {
                float rm = tm[r];
#pragma unroll
                for (int off = 1; off < 16; off <<= 1) rm = fmaxf(rm, __shfl_xor(rm, off, 64));
                float mnew  = fmaxf(m_run[r], rm);
                float alpha = __builtin_amdgcn_exp2f(m_run[r] - mnew);
                m_run[r] = mnew;
                l_part[r] *= alpha;
#pragma unroll
                for (int dt = 0; dt < 4; dt++) o_acc[dt][r] *= alpha;
            }
        }

#pragma unroll
        for (int nt = 0; nt < 4; nt++) {
#pragma unroll
            for (int r = 0; r < 4; r++) {
                float p = __builtin_amdgcn_exp2f(s[nt][r] - m_run[r]);
                l_part[r] += p;
                Ps[wave * 16 * LDP + (quad * 4 + r) * LDP + nt * 16 + lane15] = (bf16)p;
            }
        }
        asm volatile("s_waitcnt lgkmcnt(0)" ::: "memory");
        __builtin_amdgcn_sched_barrier(0);
#pragma unroll
        for (int kk = 0; kk < 2; kk++) {
            bf16x8 pf = *(const bf16x8*)(&Ps[wave * 16 * LDP + lane15 * LDP + kk * 32 + quad * 8]);
#pragma unroll
            for (int dt = 0; dt < 4; dt++) {
                bf16x8 vf = *(const bf16x8*)(&Vs[cur][(dt * 2 + kk) * 512 + lane * 8]);
                o_acc[dt] = __builtin_amdgcn_mfma_f32_16x16x32_bf16(pf, vf, o_acc[dt], 0, 0, 0);
            }
        }
        if (kt + 1 < 24) {
            asm volatile("s_waitcnt vmcnt(0)" ::: "memory");
            __builtin_amdgcn_s_barrier();
            __builtin_amdgcn_sched_barrier(0);
        }
        cur ^= 1;
    }

    float l_inv[4];
#pragma unroll
    for (int r = 0; r < 4; r++) {
        float ls = l_part[r];
#pragma unroll
        for (int off = 1; off < 16; off <<= 1) ls += __shfl_xor(ls, off, 64);
        l_inv[r] = 1.0f / ls;
    }

#pragma unroll
    for (int dt = 0; dt < 4; dt++) {
#pragma unroll
        for (int r = 0; r < 4; r++) {
            int row = q0 + wave * 16 + quad * 4 + r;
            if (row < S) {
                float v = o_acc[dt][r] * l_inv[r];
                O[headoff + (size_t)row * C + dt * 16 + lane15] = (bf16)v;
            }
        }
    }
}

extern "C" void kernel_launch(void* const* d_in, const int* in_sizes, int n_in,
                              void* d_out, int out_size, void* d_ws, size_t ws_size,
                              hipStream_t stream) {
    float* out = (float*)d_out;
    const float* x_f32 = (const float*)d_in[0];
    const int M = 6000, Cc = 1024, F = 4096, Aa = 256;
    const size_t MC = (size_t)M * Cc;
    const size_t VT_ELEMS = (size_t)64 * 64 * 1536;
    bf16* ws = (bf16*)d_ws;

    bf16* h1   = ws;                         // [M,C]
    bf16* kbuf = ws + MC;                    // [M,C]
    bf16* Vt   = ws + 2 * MC;                // [64][64][1536]
    bf16* g    = ws + 2 * MC + VT_ELEMS;     // [M,F]
    bf16* q    = (bf16*)d_out;               // d_out spare half as bf16 scratch
    bf16* wv   = h1;
    bf16* x1   = q;
    bf16* h2   = kbuf;
    bf16* x2   = Vt;
    bf16* aact = kbuf;

    size_t off = 2 * MC + VT_ELEMS + (size_t)M * F;
    bf16* Wqkv = ws + off; off += (size_t)3 * 1024 * 1024;
    bf16* bqkv = ws + off; off += 3072;
    bf16* sWo  = ws + off; off += (size_t)1024 * 1024;
    bf16* sbo  = ws + off; off += 1024;
    bf16* slnw = ws + off; off += 1024;
    bf16* slnb = ws + off; off += 1024;
    bf16* sW1  = ws + off; off += (size_t)4096 * 1024;
    bf16* sb1  = ws + off; off += 4096;
    bf16* sW2  = ws + off; off += (size_t)1024 * 4096;
    bf16* sb2  = ws + off; off += 1024;
    bf16* sln2w = ws + off; off += 1024;
    bf16* sln2b = ws + off; off += 1024;
    bf16* sWds = ws + off; off += (size_t)256 * 1024;
    bf16* sbds = ws + off; off += 256;
    bf16* sWus = ws + off; off += (size_t)1024 * 256;
    bf16* sbus = ws + off; off += 1024;

    ConvArgs ca;
    const int srcidx[19] = {1, 3, 4, 2, 5, 6, 7, 8, 9, 10, 11, 12, 13, 14, 15, 16, 17, 18, 19};
    bf16* dsts[19] = {Wqkv, Wqkv + 1048576, Wqkv + 2097152, bqkv, bqkv + 2048,
                      sWo, sbo, slnw, slnb, sW1, sb1, sW2, sb2, sln2w, sln2b,
                      sWds, sbds, sWus, sbus};
    int bacc = 0;
    for (int i = 0; i < 19; i++) {
        ca.src[i] = (const float*)d_in[srcidx[i]];
        ca.dst[i] = dsts[i];
        ca.n[i] = in_sizes[srcidx[i]];
        ca.bstart[i] = bacc;
        bacc += (ca.n[i] + 2047) / 2048;
    }
    ca.bstart[19] = bacc;

    dim3 blk(256);
    dim3 blk512(512);
    convert_many<<<bacc, blk, 0, stream>>>(ca);
    zero_kernel<<<4, blk, 0, stream>>>(bqkv + 1024, 1024);   // no k-bias

    const float scale = 0.35355339059327373f;  // 64^-0.25
    const int gmT = 47, mQ = 12;               // 128-tiles
    auto grid_for = [&](int gnT) { int nQ = (gnT + 1) >> 1; return dim3(8 * mQ * nQ); };
    const int gmT2 = 24, mQ2 = 6;              // 256-tiles
    auto grid256_for = [&](int gnT) { int nQ = (gnT + 1) >> 1; return dim3(8 * mQ2 * nQ); };

    ln_kernel<float><<<M, blk, 0, stream>>>(x_f32, slnw, slnb, h1);
    gemm256_kernel<0, 2, bf16, bf16><<<grid256_for(12), blk512, 0, stream>>>(
        h1, Wqkv, bqkv, (const bf16*)nullptr, q, kbuf, Vt, M, 3072, Cc, scale, gmT2, 12, mQ2);
    dim3 ga(24, 64);
    flash_attn_kernel<<<ga, blk, 0, stream>>>(q, kbuf, Vt, wv);
    gemm_kernel<0, 0, float, bf16><<<grid_for(8), blk, 0, stream>>>(
        wv, sWo, sbo, x_f32, x1, nullptr, nullptr, M, Cc, Cc, 1.0f, gmT, 8, mQ);
    ln_kernel<bf16><<<M, blk, 0, stream>>>(x1, sln2w, sln2b, h2);
    gemm256_kernel<1, 0, bf16, bf16><<<grid256_for(16), blk512, 0, stream>>>(
        h2, sW1, sb1, (const bf16*)nullptr, g, nullptr, nullptr, M, F, Cc, 1.0f, gmT2, 16, mQ2);
    gemm_kernel<0, 0, bf16, bf16><<<grid_for(8), blk, 0, stream>>>(
        g, sW2, sb2, x1, x2, nullptr, nullptr, M, Cc, F, 1.0f, gmT, 8, mQ);
    gemm_kernel<1, 0, bf16, bf16><<<grid_for(2), blk, 0, stream>>>(
        x2, sWds, sbds, (const bf16*)nullptr, aact, nullptr, nullptr, M, Aa, Cc, 1.0f, gmT, 2, mQ);
    gemm_kernel<0, 0, bf16, float><<<grid_for(8), blk, 0, stream>>>(
        aact, sWus, sbus, x2, out, nullptr, nullptr, M, Cc, Aa, 1.0f, gmT, 8, mQ);
}

// Round 6
// 756.342 us; speedup vs baseline: 1.5212x; 1.1265x over previous
//
#include <hip/hip_runtime.h>
#include <hip/hip_bf16.h>
#include <math.h>

typedef __bf16 bf16;
typedef __bf16 bf16x8 __attribute__((ext_vector_type(8)));
typedef float  f32x4  __attribute__((ext_vector_type(4)));

// async global->LDS, 16 B per lane; LDS dest = wave-uniform base + lane*16
__device__ __forceinline__ void load16_lds(const bf16* g, bf16* l) {
    __builtin_amdgcn_global_load_lds(
        (__attribute__((address_space(1))) void*)(g),
        (__attribute__((address_space(3))) void*)(l), 16, 0, 0);
}

// tanh-form GELU (max abs err vs exact erf-GELU ~7e-4)
__device__ __forceinline__ float gelu_f(float x) {
    float u = 1.5957691216057308f * (x + 0.044715f * x * x * x);  // 2*sqrt(2/pi)*(...)
    float e = __expf(u);
    float th = 1.0f - 2.0f / (1.0f + e);
    return 0.5f * x * (1.0f + th);
}

// ---------------- fused weight converts ----------------
struct ConvArgs {
    const float* src[19];
    bf16* dst[19];
    int n[19];
    int bstart[20];
};
__global__ __launch_bounds__(256) void convert_many(ConvArgs a) {
    int blk = blockIdx.x;
    int s = 0;
    while (blk >= a.bstart[s + 1]) s++;
    const float* src = a.src[s];
    bf16* dst = a.dst[s];
    int n = a.n[s];
    int i0 = (blk - a.bstart[s]) * 2048;
#pragma unroll
    for (int e = 0; e < 8; e++) {
        int i = i0 + threadIdx.x + e * 256;
        if (i < n) dst[i] = (bf16)src[i];
    }
}

__global__ void zero_kernel(bf16* dst, int n) {
    int i = blockIdx.x * blockDim.x + threadIdx.x;
    if (i < n) dst[i] = (bf16)0.0f;
}

// ---------------- split-K reduce: out = [gelu](P0+P1+bias) [+resid] ----------------
template<int ACT, int RES>
__global__ __launch_bounds__(256) void reduce_kernel(
    const bf16* __restrict__ P0, const bf16* __restrict__ P1,
    const bf16* __restrict__ bias, const bf16* __restrict__ resid,
    bf16* __restrict__ out, int nmask, int total)
{
    int i = (blockIdx.x * 256 + threadIdx.x) * 8;
    if (i >= total) return;
    bf16x8 p0 = *(const bf16x8*)(P0 + i);
    bf16x8 p1 = *(const bf16x8*)(P1 + i);
    bf16x8 bb = *(const bf16x8*)(bias + (i & nmask));
    bf16x8 rr;
    if (RES) rr = *(const bf16x8*)(resid + i);
    bf16x8 o;
#pragma unroll
    for (int j = 0; j < 8; j++) {
        float v = (float)p0[j] + (float)p1[j] + (float)bb[j];
        if (ACT) v = gelu_f(v);
        if (RES) v += (float)rr[j];
        o[j] = (bf16)v;
    }
    *(bf16x8*)(out + i) = o;
}

// ---------------- LayerNorm ----------------
template<class XT>
__global__ __launch_bounds__(256) void ln_kernel(
    const XT* __restrict__ X, const bf16* __restrict__ w,
    const bf16* __restrict__ b, bf16* __restrict__ out)
{
    const int C = 1024;
    const int row = blockIdx.x;
    const int tid = threadIdx.x;
    const XT* xr = X + (size_t)row * C;
    float x0 = (float)xr[tid * 4 + 0], x1 = (float)xr[tid * 4 + 1];
    float x2 = (float)xr[tid * 4 + 2], x3 = (float)xr[tid * 4 + 3];
    float s  = x0 + x1 + x2 + x3;
    float sq = x0*x0 + x1*x1 + x2*x2 + x3*x3;
#pragma unroll
    for (int off = 32; off >= 1; off >>= 1) {
        s  += __shfl_xor(s,  off, 64);
        sq += __shfl_xor(sq, off, 64);
    }
    __shared__ float red[8];
    int wave = tid >> 6;
    if ((tid & 63) == 0) { red[wave] = s; red[4 + wave] = sq; }
    __syncthreads();
    float ts = red[0] + red[1] + red[2] + red[3];
    float tq = red[4] + red[5] + red[6] + red[7];
    float mean = ts * (1.0f / C);
    float var  = tq * (1.0f / C) - mean * mean;
    float rstd = rsqrtf(var + 1e-5f);
    float w0 = (float)w[tid*4+0], w1 = (float)w[tid*4+1], w2 = (float)w[tid*4+2], w3 = (float)w[tid*4+3];
    float b0 = (float)b[tid*4+0], b1 = (float)b[tid*4+1], b2 = (float)b[tid*4+2], b3 = (float)b[tid*4+3];
    bf16* orow = out + (size_t)row * C + tid * 4;
    orow[0] = (bf16)((x0 - mean) * rstd * w0 + b0);
    orow[1] = (bf16)((x1 - mean) * rstd * w1 + b1);
    orow[2] = (bf16)((x2 - mean) * rstd * w2 + b2);
    orow[3] = (bf16)((x3 - mean) * rstd * w3 + b3);
}

// ---------------- GEMM 128x128 (single-buffer; verified baseline) ----------------
// out = act((A[M,K] @ W[N,K]^T + bias)*scale) + resid
// OMODE 0: normal; 2: fused QKV split; 3: split-K partial (blockIdx.y selects
//          K-half and output buffer: y=0 -> out, y=1 -> out_k; raw bf16, no
//          bias/scale/act/resid -- combined later by reduce_kernel).
// ldK = row stride of A and W (full K); K = this block's K extent.
template<int ACT, int OMODE, class RT, class OT>
__global__ __launch_bounds__(256) void gemm_kernel(
    const bf16* __restrict__ A, const bf16* __restrict__ W,
    const bf16* __restrict__ bias, const RT* __restrict__ resid,
    OT* __restrict__ out, bf16* __restrict__ out_k, bf16* __restrict__ out_v,
    int M, int N, int K, float scale, int gmT, int gnT, int mQ, int ldK)
{
    const int lin = blockIdx.x;
    const int xcd = lin & 7;
    const int t_  = lin >> 3;
    const int mt_ = (xcd & 3) + 4 * (t_ % mQ);
    const int nt_ = (xcd >> 2) + 2 * (t_ / mQ);
    if (mt_ >= gmT || nt_ >= gnT) return;
    const int m0 = mt_ * 128;
    const int n0 = nt_ * 128;
    const int ksp = (OMODE == 3) ? blockIdx.y : 0;
    const size_t ko = (size_t)ksp * K;

    __shared__ __align__(16) bf16 As[16 * 512];   // chunk (msub*2+kk): 1 KB each
    __shared__ __align__(16) bf16 Bs[16 * 512];
    const int tid = threadIdx.x;
    const int wave = tid >> 6, lane = tid & 63;
    const int lane15 = lane & 15, quad = lane >> 4;
    const int wm0 = (wave >> 1) * 64;
    const int wn0 = (wave & 1) * 64;
    f32x4 acc[4][4] = {};

    int ra0 = m0 + (2 * wave)     * 16 + lane15; if (ra0 > M - 1) ra0 = M - 1;
    int ra1 = m0 + (2 * wave + 1) * 16 + lane15; if (ra1 > M - 1) ra1 = M - 1;
    const int rb0 = n0 + (2 * wave)     * 16 + lane15;
    const int rb1 = n0 + (2 * wave + 1) * 16 + lane15;
    const bf16* a0 = A + (size_t)ra0 * ldK + ko + quad * 8;
    const bf16* a1 = A + (size_t)ra1 * ldK + ko + quad * 8;
    const bf16* w0 = W + (size_t)rb0 * ldK + ko + quad * 8;
    const bf16* w1 = W + (size_t)rb1 * ldK + ko + quad * 8;

    for (int k0 = 0; k0 < K; k0 += 64) {
#pragma unroll
        for (int kk = 0; kk < 2; kk++) {
            load16_lds(a0 + k0 + kk * 32, &As[((2 * wave)     * 2 + kk) * 512]);
            load16_lds(a1 + k0 + kk * 32, &As[((2 * wave + 1) * 2 + kk) * 512]);
            load16_lds(w0 + k0 + kk * 32, &Bs[((2 * wave)     * 2 + kk) * 512]);
            load16_lds(w1 + k0 + kk * 32, &Bs[((2 * wave + 1) * 2 + kk) * 512]);
        }
        __syncthreads();
#pragma unroll
        for (int kk = 0; kk < 2; kk++) {
            bf16x8 af[4], bfr[4];
#pragma unroll
            for (int tt = 0; tt < 4; tt++) {
                af[tt]  = *(const bf16x8*)(&As[(((wm0 >> 4) + tt) * 2 + kk) * 512 + lane * 8]);
                bfr[tt] = *(const bf16x8*)(&Bs[(((wn0 >> 4) + tt) * 2 + kk) * 512 + lane * 8]);
            }
#pragma unroll
            for (int mt = 0; mt < 4; mt++)
#pragma unroll
                for (int nt = 0; nt < 4; nt++)
                    acc[mt][nt] = __builtin_amdgcn_mfma_f32_16x16x32_bf16(
                        af[mt], bfr[nt], acc[mt][nt], 0, 0, 0);
        }
        __syncthreads();
    }

    // epilogue: C/D layout col=lane&15, row=quad*4+reg
#pragma unroll
    for (int mt = 0; mt < 4; mt++) {
#pragma unroll
        for (int r = 0; r < 4; r++) {
            int gm = m0 + wm0 + mt * 16 + quad * 4 + r;
            if (gm >= M) continue;
#pragma unroll
            for (int nt = 0; nt < 4; nt++) {
                int gn = n0 + wn0 + nt * 16 + lane15;
                float v = acc[mt][nt][r];
                if (OMODE == 3) {
                    bf16* po = ksp ? out_k : (bf16*)out;
                    po[(size_t)gm * N + gn] = (bf16)v;
                    continue;
                }
                if (bias) v += (float)bias[gn];
                if (OMODE == 2) {
                    if (gn < 2048) {
                        v *= scale;
                        if (gn < 1024) v *= 1.4426950408889634f;  // exp2-domain softmax
                    }
                } else v *= scale;
                if (ACT == 1) v = gelu_f(v);
                if (OMODE == 2) {
                    if (gn < 1024) {
                        ((bf16*)out)[(size_t)gm * 1024 + gn] = (bf16)v;            // q
                    } else if (gn < 2048) {
                        out_k[(size_t)gm * 1024 + (gn - 1024)] = (bf16)v;          // k
                    } else {
                        int gg = gn - 2048;
                        int bb = gm / 1500;
                        int ss = gm - bb * 1500;
                        int hh = gg >> 6, dd = gg & 63;
                        out_v[(((size_t)bb * 16 + hh) * 64 + dd) * 1536 + ss] = (bf16)v;  // v^T
                    }
                } else {
                    if (resid) v += (float)resid[(size_t)gm * N + gn];
                    out[(size_t)gm * N + gn] = (OT)v;
                }
            }
        }
    }
}

// ---------------- Flash attention (2-phase double-buffered K/V) ----------------
__global__ __launch_bounds__(256) void flash_attn_kernel(
    const bf16* __restrict__ Q, const bf16* __restrict__ Km,
    const bf16* __restrict__ Vt, bf16* __restrict__ O)
{
    const int S = 1500, C = 1024, SP = 1536;
    const int LDP = 72;
    __shared__ __align__(16) bf16 Ks[2][8 * 512];
    __shared__ __align__(16) bf16 Vs[2][8 * 512];
    __shared__ __align__(16) bf16 Ps[4 * 16 * LDP];
    const int tid = threadIdx.x;
    const int wave = tid >> 6, lane = tid & 63;
    const int lane15 = lane & 15, quad = lane >> 4;
    const int bh = blockIdx.y;
    const int q0 = blockIdx.x * 64;
    const size_t headoff = (size_t)(bh >> 4) * S * C + (size_t)(bh & 15) * 64;
    const size_t vtoff   = (size_t)bh * 64 * SP;

    bf16x8 qf[2];
    int qr = q0 + wave * 16 + lane15; if (qr > S - 1) qr = S - 1;
    qf[0] = *(const bf16x8*)(Q + headoff + (size_t)qr * C + quad * 8);
    qf[1] = *(const bf16x8*)(Q + headoff + (size_t)qr * C + 32 + quad * 8);

    const bf16* vbase = Vt + vtoff + (size_t)(wave * 16 + lane15) * SP + quad * 8;

    auto stageKV = [&](int buf, int kt) {
        const int j0 = kt * 64;
        int kr = j0 + wave * 16 + lane15; if (kr > S - 1) kr = S - 1;
        const bf16* kbase = Km + headoff + (size_t)kr * C + quad * 8;
#pragma unroll
        for (int kk = 0; kk < 2; kk++) {
            load16_lds(kbase + kk * 32,      &Ks[buf][(wave * 2 + kk) * 512]);
            load16_lds(vbase + j0 + kk * 32, &Vs[buf][(wave * 2 + kk) * 512]);
        }
    };

    float m_run[4], l_part[4];
    f32x4 o_acc[4] = {};
#pragma unroll
    for (int r = 0; r < 4; r++) { m_run[r] = 4.0f; l_part[r] = 0.0f; }

    stageKV(0, 0);
    asm volatile("s_waitcnt vmcnt(0)" ::: "memory");
    __builtin_amdgcn_s_barrier();
    __builtin_amdgcn_sched_barrier(0);

    int cur = 0;
    for (int kt = 0; kt < 24; kt++) {
        if (kt + 1 < 24) stageKV(cur ^ 1, kt + 1);
        const int j0 = kt * 64;

        f32x4 s[4] = {};
#pragma unroll
        for (int kk = 0; kk < 2; kk++) {
#pragma unroll
            for (int nt = 0; nt < 4; nt++) {
                bf16x8 kf = *(const bf16x8*)(&Ks[cur][(nt * 2 + kk) * 512 + lane * 8]);
                s[nt] = __builtin_amdgcn_mfma_f32_16x16x32_bf16(qf[kk], kf, s[nt], 0, 0, 0);
            }
        }
        if (kt == 23) {
#pragma unroll
            for (int nt = 0; nt < 4; nt++) {
                if (j0 + nt * 16 + lane15 >= S) {
#pragma unroll
                    for (int r = 0; r < 4; r++) s[nt][r] = -1e30f;
                }
            }
        }

        float tm[4];
#pragma unroll
        for (int r = 0; r < 4; r++)
            tm[r] = fmaxf(fmaxf(s[0][r], s[1][r]), fmaxf(s[2][r], s[3][r]));
        bool rec = (tm[0] > m_run[0]) | (tm[1] > m_run[1]) |
                   (tm[2] > m_run[2]) | (tm[3] > m_run[3]);
        if (__any(rec)) {
#pragma unroll
            for (int r = 0; r < 4; r++) {
                float rm = tm[r];
#pragma unroll
                for (int off = 1; off < 16; off <<= 1) rm = fmaxf(rm, __shfl_xor(rm, off, 64));
                float mnew  = fmaxf(m_run[r], rm);
                float alpha = __builtin_amdgcn_exp2f(m_run[r] - mnew);
                m_run[r] = mnew;
                l_part[r] *= alpha;
#pragma unroll
                for (int dt = 0; dt < 4; dt++) o_acc[dt][r] *= alpha;
            }
        }

#pragma unroll
        for (int nt = 0; nt < 4; nt++) {
#pragma unroll
            for (int r = 0; r < 4; r++) {
                float p = __builtin_amdgcn_exp2f(s[nt][r] - m_run[r]);
                l_part[r] += p;
                Ps[wave * 16 * LDP + (quad * 4 + r) * LDP + nt * 16 + lane15] = (bf16)p;
            }
        }
        asm volatile("s_waitcnt lgkmcnt(0)" ::: "memory");
        __builtin_amdgcn_sched_barrier(0);
#pragma unroll
        for (int kk = 0; kk < 2; kk++) {
            bf16x8 pf = *(const bf16x8*)(&Ps[wave * 16 * LDP + lane15 * LDP + kk * 32 + quad * 8]);
#pragma unroll
            for (int dt = 0; dt < 4; dt++) {
                bf16x8 vf = *(const bf16x8*)(&Vs[cur][(dt * 2 + kk) * 512 + lane * 8]);
                o_acc[dt] = __builtin_amdgcn_mfma_f32_16x16x32_bf16(pf, vf, o_acc[dt], 0, 0, 0);
            }
        }
        if (kt + 1 < 24) {
            asm volatile("s_waitcnt vmcnt(0)" ::: "memory");
            __builtin_amdgcn_s_barrier();
            __builtin_amdgcn_sched_barrier(0);
        }
        cur ^= 1;
    }

    float l_inv[4];
#pragma unroll
    for (int r = 0; r < 4; r++) {
        float ls = l_part[r];
#pragma unroll
        for (int off = 1; off < 16; off <<= 1) ls += __shfl_xor(ls, off, 64);
        l_inv[r] = 1.0f / ls;
    }

#pragma unroll
    for (int dt = 0; dt < 4; dt++) {
#pragma unroll
        for (int r = 0; r < 4; r++) {
            int row = q0 + wave * 16 + quad * 4 + r;
            if (row < S) {
                float v = o_acc[dt][r] * l_inv[r];
                O[headoff + (size_t)row * C + dt * 16 + lane15] = (bf16)v;
            }
        }
    }
}

extern "C" void kernel_launch(void* const* d_in, const int* in_sizes, int n_in,
                              void* d_out, int out_size, void* d_ws, size_t ws_size,
                              hipStream_t stream) {
    float* out = (float*)d_out;
    const float* x_f32 = (const float*)d_in[0];
    const int M = 6000, Cc = 1024, F = 4096, Aa = 256;
    const size_t MC = (size_t)M * Cc;
    const size_t VT_ELEMS = (size_t)64 * 64 * 1536;
    bf16* ws = (bf16*)d_ws;

    bf16* h1   = ws;                         // [M,C]
    bf16* kbuf = ws + MC;                    // [M,C]
    bf16* Vt   = ws + 2 * MC;                // [64][64][1536]
    bf16* g    = ws + 2 * MC + VT_ELEMS;     // [M,F]
    bf16* q    = (bf16*)d_out;               // d_out spare half as bf16 scratch
    bf16* wv   = h1;
    bf16* x1   = q;
    bf16* h2   = kbuf;
    bf16* x2   = Vt;
    bf16* aact = kbuf;
    // split-K partial buffers (regions dead at time of use):
    bf16* P0   = kbuf;                       // free during W2 (h2 consumed by W1)
    bf16* P1   = h1;                         // free during W2 (wv consumed by Wo)
    bf16* P0d  = h1;                         // free during Wds (P1 consumed by reduce)
    bf16* P1d  = h1 + (size_t)M * Aa;        // second 3 MB of h1 region

    size_t off = 2 * MC + VT_ELEMS + (size_t)M * F;
    bf16* Wqkv = ws + off; off += (size_t)3 * 1024 * 1024;
    bf16* bqkv = ws + off; off += 3072;
    bf16* sWo  = ws + off; off += (size_t)1024 * 1024;
    bf16* sbo  = ws + off; off += 1024;
    bf16* slnw = ws + off; off += 1024;
    bf16* slnb = ws + off; off += 1024;
    bf16* sW1  = ws + off; off += (size_t)4096 * 1024;
    bf16* sb1  = ws + off; off += 4096;
    bf16* sW2  = ws + off; off += (size_t)1024 * 4096;
    bf16* sb2  = ws + off; off += 1024;
    bf16* sln2w = ws + off; off += 1024;
    bf16* sln2b = ws + off; off += 1024;
    bf16* sWds = ws + off; off += (size_t)256 * 1024;
    bf16* sbds = ws + off; off += 256;
    bf16* sWus = ws + off; off += (size_t)1024 * 256;
    bf16* sbus = ws + off; off += 1024;

    ConvArgs ca;
    const int srcidx[19] = {1, 3, 4, 2, 5, 6, 7, 8, 9, 10, 11, 12, 13, 14, 15, 16, 17, 18, 19};
    bf16* dsts[19] = {Wqkv, Wqkv + 1048576, Wqkv + 2097152, bqkv, bqkv + 2048,
                      sWo, sbo, slnw, slnb, sW1, sb1, sW2, sb2, sln2w, sln2b,
                      sWds, sbds, sWus, sbus};
    int bacc = 0;
    for (int i = 0; i < 19; i++) {
        ca.src[i] = (const float*)d_in[srcidx[i]];
        ca.dst[i] = dsts[i];
        ca.n[i] = in_sizes[srcidx[i]];
        ca.bstart[i] = bacc;
        bacc += (ca.n[i] + 2047) / 2048;
    }
    ca.bstart[19] = bacc;

    dim3 blk(256);
    convert_many<<<bacc, blk, 0, stream>>>(ca);
    zero_kernel<<<4, blk, 0, stream>>>(bqkv + 1024, 1024);   // no k-bias

    const float scale = 0.35355339059327373f;  // 64^-0.25
    const int gmT = 47, mQ = 12;               // ceil(47/4)
    auto grid_for = [&](int gnT) { int nQ = (gnT + 1) >> 1; return dim3(8 * mQ * nQ); };

    ln_kernel<float><<<M, blk, 0, stream>>>(x_f32, slnw, slnb, h1);
    gemm_kernel<0, 2, bf16, bf16><<<grid_for(24), blk, 0, stream>>>(
        h1, Wqkv, bqkv, (const bf16*)nullptr, q, kbuf, Vt, M, 3072, Cc, scale, gmT, 24, mQ, Cc);
    dim3 ga(24, 64);
    flash_attn_kernel<<<ga, blk, 0, stream>>>(q, kbuf, Vt, wv);
    gemm_kernel<0, 0, float, bf16><<<grid_for(8), blk, 0, stream>>>(
        wv, sWo, sbo, x_f32, x1, nullptr, nullptr, M, Cc, Cc, 1.0f, gmT, 8, mQ, Cc);
    ln_kernel<bf16><<<M, blk, 0, stream>>>(x1, sln2w, sln2b, h2);
    gemm_kernel<1, 0, bf16, bf16><<<grid_for(32), blk, 0, stream>>>(
        h2, sW1, sb1, (const bf16*)nullptr, g, nullptr, nullptr, M, F, Cc, 1.0f, gmT, 32, mQ, Cc);

    // ---- W2 with split-K=2: partials P0/P1, then reduce (+b2, +x1 resid) -> x2
    {
        dim3 gr = grid_for(8); gr.y = 2;
        gemm_kernel<0, 3, bf16, bf16><<<gr, blk, 0, stream>>>(
            g, sW2, nullptr, (const bf16*)nullptr, P0, P1, nullptr,
            M, Cc, F / 2, 1.0f, gmT, 8, mQ, F);
        reduce_kernel<0, 1><<<(M * Cc) / 2048, blk, 0, stream>>>(
            P0, P1, sb2, x1, x2, Cc - 1, M * Cc);
    }

    // ---- adapter down (Wds) with split-K=2: partials, then gelu-reduce -> aact
    {
        dim3 gr = grid_for(2); gr.y = 2;
        gemm_kernel<0, 3, bf16, bf16><<<gr, blk, 0, stream>>>(
            x2, sWds, nullptr, (const bf16*)nullptr, P0d, P1d, nullptr,
            M, Aa, Cc / 2, 1.0f, gmT, 2, mQ, Cc);
        reduce_kernel<1, 0><<<(M * Aa) / 2048, blk, 0, stream>>>(
            P0d, P1d, sbds, nullptr, aact, Aa - 1, M * Aa);
    }

    gemm_kernel<0, 0, bf16, float><<<grid_for(8), blk, 0, stream>>>(
        aact, sWus, sbus, x2, out, nullptr, nullptr, M, Cc, Aa, 1.0f, gmT, 8, mQ, Aa);
}

// Round 7
// 750.574 us; speedup vs baseline: 1.5329x; 1.0077x over previous
//
#include <hip/hip_runtime.h>
#include <hip/hip_bf16.h>
#include <math.h>

typedef __bf16 bf16;
typedef __bf16 bf16x8 __attribute__((ext_vector_type(8)));
typedef float  f32x4  __attribute__((ext_vector_type(4)));

// async global->LDS, 16 B per lane; LDS dest = wave-uniform base + lane*16
__device__ __forceinline__ void load16_lds(const bf16* g, bf16* l) {
    __builtin_amdgcn_global_load_lds(
        (__attribute__((address_space(1))) void*)(g),
        (__attribute__((address_space(3))) void*)(l), 16, 0, 0);
}

// tanh-form GELU (max abs err vs exact erf-GELU ~7e-4)
__device__ __forceinline__ float gelu_f(float x) {
    float u = 1.5957691216057308f * (x + 0.044715f * x * x * x);  // 2*sqrt(2/pi)*(...)
    float e = __expf(u);
    float th = 1.0f - 2.0f / (1.0f + e);
    return 0.5f * x * (1.0f + th);
}

// ---------------- fused weight converts ----------------
struct ConvArgs {
    const float* src[19];
    bf16* dst[19];
    int n[19];
    int bstart[20];
};
__global__ __launch_bounds__(256) void convert_many(ConvArgs a) {
    int blk = blockIdx.x;
    int s = 0;
    while (blk >= a.bstart[s + 1]) s++;
    const float* src = a.src[s];
    bf16* dst = a.dst[s];
    int n = a.n[s];
    int i0 = (blk - a.bstart[s]) * 2048;
#pragma unroll
    for (int e = 0; e < 8; e++) {
        int i = i0 + threadIdx.x + e * 256;
        if (i < n) dst[i] = (bf16)src[i];
    }
}

__global__ void zero_kernel(bf16* dst, int n) {
    int i = blockIdx.x * blockDim.x + threadIdx.x;
    if (i < n) dst[i] = (bf16)0.0f;
}

// ---------------- split-K reduce: out = [gelu](P0+P1+bias) [+resid] ----------------
template<int ACT, int RES, class RT, class OT>
__global__ __launch_bounds__(256) void reduce_kernel(
    const bf16* __restrict__ P0, const bf16* __restrict__ P1,
    const bf16* __restrict__ bias, const RT* __restrict__ resid,
    OT* __restrict__ out, int nmask, int total)
{
    int i = (blockIdx.x * 256 + threadIdx.x) * 8;
    if (i >= total) return;
    bf16x8 p0 = *(const bf16x8*)(P0 + i);
    bf16x8 p1 = *(const bf16x8*)(P1 + i);
    bf16x8 bb = *(const bf16x8*)(bias + (i & nmask));
#pragma unroll
    for (int j = 0; j < 8; j++) {
        float v = (float)p0[j] + (float)p1[j] + (float)bb[j];
        if (ACT) v = gelu_f(v);
        if (RES) v += (float)resid[i + j];
        out[i + j] = (OT)v;
    }
}

// ---------------- LayerNorm ----------------
template<class XT>
__global__ __launch_bounds__(256) void ln_kernel(
    const XT* __restrict__ X, const bf16* __restrict__ w,
    const bf16* __restrict__ b, bf16* __restrict__ out)
{
    const int C = 1024;
    const int row = blockIdx.x;
    const int tid = threadIdx.x;
    const XT* xr = X + (size_t)row * C;
    float x0 = (float)xr[tid * 4 + 0], x1 = (float)xr[tid * 4 + 1];
    float x2 = (float)xr[tid * 4 + 2], x3 = (float)xr[tid * 4 + 3];
    float s  = x0 + x1 + x2 + x3;
    float sq = x0*x0 + x1*x1 + x2*x2 + x3*x3;
#pragma unroll
    for (int off = 32; off >= 1; off >>= 1) {
        s  += __shfl_xor(s,  off, 64);
        sq += __shfl_xor(sq, off, 64);
    }
    __shared__ float red[8];
    int wave = tid >> 6;
    if ((tid & 63) == 0) { red[wave] = s; red[4 + wave] = sq; }
    __syncthreads();
    float ts = red[0] + red[1] + red[2] + red[3];
    float tq = red[4] + red[5] + red[6] + red[7];
    float mean = ts * (1.0f / C);
    float var  = tq * (1.0f / C) - mean * mean;
    float rstd = rsqrtf(var + 1e-5f);
    float w0 = (float)w[tid*4+0], w1 = (float)w[tid*4+1], w2 = (float)w[tid*4+2], w3 = (float)w[tid*4+3];
    float b0 = (float)b[tid*4+0], b1 = (float)b[tid*4+1], b2 = (float)b[tid*4+2], b3 = (float)b[tid*4+3];
    bf16* orow = out + (size_t)row * C + tid * 4;
    orow[0] = (bf16)((x0 - mean) * rstd * w0 + b0);
    orow[1] = (bf16)((x1 - mean) * rstd * w1 + b1);
    orow[2] = (bf16)((x2 - mean) * rstd * w2 + b2);
    orow[3] = (bf16)((x3 - mean) * rstd * w3 + b3);
}

// ---------------- GEMM 128x128, BK = 32*BK2 (single-buffer r1 structure) ----------------
// out = act((A[M,K] @ W[N,K]^T + bias)*scale) + resid
// BK2=4 -> BK=128: 2x work per barrier pair amortizes the ~2300-cyc load latency
// (serial/step ~= lat + BK2*~250cyc compute). LDS = BK2*16 KB.
// OMODE 0: normal; 2: fused QKV split; 3: split-K partial (blockIdx.y selects
//          K-half and output buffer: y=0 -> out, y=1 -> out_k; raw bf16).
// ldK = row stride of A and W (full K); K = this block's K extent.
template<int ACT, int OMODE, int BK2, class RT, class OT>
__global__ __launch_bounds__(256) void gemm_kernel(
    const bf16* __restrict__ A, const bf16* __restrict__ W,
    const bf16* __restrict__ bias, const RT* __restrict__ resid,
    OT* __restrict__ out, bf16* __restrict__ out_k, bf16* __restrict__ out_v,
    int M, int N, int K, float scale, int gmT, int gnT, int mQ, int ldK)
{
    const int lin = blockIdx.x;
    const int xcd = lin & 7;
    const int t_  = lin >> 3;
    const int mt_ = (xcd & 3) + 4 * (t_ % mQ);
    const int nt_ = (xcd >> 2) + 2 * (t_ / mQ);
    if (mt_ >= gmT || nt_ >= gnT) return;
    const int m0 = mt_ * 128;
    const int n0 = nt_ * 128;
    const int ksp = (OMODE == 3) ? blockIdx.y : 0;
    const size_t ko = (size_t)ksp * K;

    __shared__ __align__(16) bf16 As[8 * BK2 * 512];   // chunk (msub*BK2+kk): 1 KB each
    __shared__ __align__(16) bf16 Bs[8 * BK2 * 512];
    const int tid = threadIdx.x;
    const int wave = tid >> 6, lane = tid & 63;
    const int lane15 = lane & 15, quad = lane >> 4;
    const int wm0 = (wave >> 1) * 64;
    const int wn0 = (wave & 1) * 64;
    f32x4 acc[4][4] = {};

    int ra0 = m0 + (2 * wave)     * 16 + lane15; if (ra0 > M - 1) ra0 = M - 1;
    int ra1 = m0 + (2 * wave + 1) * 16 + lane15; if (ra1 > M - 1) ra1 = M - 1;
    const int rb0 = n0 + (2 * wave)     * 16 + lane15;
    const int rb1 = n0 + (2 * wave + 1) * 16 + lane15;
    const bf16* a0 = A + (size_t)ra0 * ldK + ko + quad * 8;
    const bf16* a1 = A + (size_t)ra1 * ldK + ko + quad * 8;
    const bf16* w0 = W + (size_t)rb0 * ldK + ko + quad * 8;
    const bf16* w1 = W + (size_t)rb1 * ldK + ko + quad * 8;

    for (int k0 = 0; k0 < K; k0 += 32 * BK2) {
#pragma unroll
        for (int kk = 0; kk < BK2; kk++) {
            load16_lds(a0 + k0 + kk * 32, &As[((2 * wave)     * BK2 + kk) * 512]);
            load16_lds(a1 + k0 + kk * 32, &As[((2 * wave + 1) * BK2 + kk) * 512]);
            load16_lds(w0 + k0 + kk * 32, &Bs[((2 * wave)     * BK2 + kk) * 512]);
            load16_lds(w1 + k0 + kk * 32, &Bs[((2 * wave + 1) * BK2 + kk) * 512]);
        }
        __syncthreads();
#pragma unroll
        for (int kk = 0; kk < BK2; kk++) {
            bf16x8 af[4], bfr[4];
#pragma unroll
            for (int tt = 0; tt < 4; tt++) {
                af[tt]  = *(const bf16x8*)(&As[(((wm0 >> 4) + tt) * BK2 + kk) * 512 + lane * 8]);
                bfr[tt] = *(const bf16x8*)(&Bs[(((wn0 >> 4) + tt) * BK2 + kk) * 512 + lane * 8]);
            }
#pragma unroll
            for (int mt = 0; mt < 4; mt++)
#pragma unroll
                for (int nt = 0; nt < 4; nt++)
                    acc[mt][nt] = __builtin_amdgcn_mfma_f32_16x16x32_bf16(
                        af[mt], bfr[nt], acc[mt][nt], 0, 0, 0);
        }
        __syncthreads();
    }

    // epilogue: C/D layout col=lane&15, row=quad*4+reg
#pragma unroll
    for (int mt = 0; mt < 4; mt++) {
#pragma unroll
        for (int r = 0; r < 4; r++) {
            int gm = m0 + wm0 + mt * 16 + quad * 4 + r;
            if (gm >= M) continue;
#pragma unroll
            for (int nt = 0; nt < 4; nt++) {
                int gn = n0 + wn0 + nt * 16 + lane15;
                float v = acc[mt][nt][r];
                if (OMODE == 3) {
                    bf16* po = ksp ? out_k : (bf16*)out;
                    po[(size_t)gm * N + gn] = (bf16)v;
                    continue;
                }
                if (bias) v += (float)bias[gn];
                if (OMODE == 2) {
                    if (gn < 2048) {
                        v *= scale;
                        if (gn < 1024) v *= 1.4426950408889634f;  // exp2-domain softmax
                    }
                } else v *= scale;
                if (ACT == 1) v = gelu_f(v);
                if (OMODE == 2) {
                    if (gn < 1024) {
                        ((bf16*)out)[(size_t)gm * 1024 + gn] = (bf16)v;            // q
                    } else if (gn < 2048) {
                        out_k[(size_t)gm * 1024 + (gn - 1024)] = (bf16)v;          // k
                    } else {
                        int gg = gn - 2048;
                        int bb = gm / 1500;
                        int ss = gm - bb * 1500;
                        int hh = gg >> 6, dd = gg & 63;
                        out_v[(((size_t)bb * 16 + hh) * 64 + dd) * 1536 + ss] = (bf16)v;  // v^T
                    }
                } else {
                    if (resid) v += (float)resid[(size_t)gm * N + gn];
                    out[(size_t)gm * N + gn] = (OT)v;
                }
            }
        }
    }
}

// ---------------- Flash attention (2-phase double-buffered K/V) ----------------
__global__ __launch_bounds__(256) void flash_attn_kernel(
    const bf16* __restrict__ Q, const bf16* __restrict__ Km,
    const bf16* __restrict__ Vt, bf16* __restrict__ O)
{
    const int S = 1500, C = 1024, SP = 1536;
    const int LDP = 72;
    __shared__ __align__(16) bf16 Ks[2][8 * 512];
    __shared__ __align__(16) bf16 Vs[2][8 * 512];
    __shared__ __align__(16) bf16 Ps[4 * 16 * LDP];
    const int tid = threadIdx.x;
    const int wave = tid >> 6, lane = tid & 63;
    const int lane15 = lane & 15, quad = lane >> 4;
    const int bh = blockIdx.y;
    const int q0 = blockIdx.x * 64;
    const size_t headoff = (size_t)(bh >> 4) * S * C + (size_t)(bh & 15) * 64;
    const size_t vtoff   = (size_t)bh * 64 * SP;

    bf16x8 qf[2];
    int qr = q0 + wave * 16 + lane15; if (qr > S - 1) qr = S - 1;
    qf[0] = *(const bf16x8*)(Q + headoff + (size_t)qr * C + quad * 8);
    qf[1] = *(const bf16x8*)(Q + headoff + (size_t)qr * C + 32 + quad * 8);

    const bf16* vbase = Vt + vtoff + (size_t)(wave * 16 + lane15) * SP + quad * 8;

    auto stageKV = [&](int buf, int kt) {
        const int j0 = kt * 64;
        int kr = j0 + wave * 16 + lane15; if (kr > S - 1) kr = S - 1;
        const bf16* kbase = Km + headoff + (size_t)kr * C + quad * 8;
#pragma unroll
        for (int kk = 0; kk < 2; kk++) {
            load16_lds(kbase + kk * 32,      &Ks[buf][(wave * 2 + kk) * 512]);
            load16_lds(vbase + j0 + kk * 32, &Vs[buf][(wave * 2 + kk) * 512]);
        }
    };

    float m_run[4], l_part[4];
    f32x4 o_acc[4] = {};
#pragma unroll
    for (int r = 0; r < 4; r++) { m_run[r] = 4.0f; l_part[r] = 0.0f; }

    stageKV(0, 0);
    asm volatile("s_waitcnt vmcnt(0)" ::: "memory");
    __builtin_amdgcn_s_barrier();
    __builtin_amdgcn_sched_barrier(0);

    int cur = 0;
    for (int kt = 0; kt < 24; kt++) {
        if (kt + 1 < 24) stageKV(cur ^ 1, kt + 1);
        const int j0 = kt * 64;

        f32x4 s[4] = {};
#pragma unroll
        for (int kk = 0; kk < 2; kk++) {
#pragma unroll
            for (int nt = 0; nt < 4; nt++) {
                bf16x8 kf = *(const bf16x8*)(&Ks[cur][(nt * 2 + kk) * 512 + lane * 8]);
                s[nt] = __builtin_amdgcn_mfma_f32_16x16x32_bf16(qf[kk], kf, s[nt], 0, 0, 0);
            }
        }
        if (kt == 23) {
#pragma unroll
            for (int nt = 0; nt < 4; nt++) {
                if (j0 + nt * 16 + lane15 >= S) {
#pragma unroll
                    for (int r = 0; r < 4; r++) s[nt][r] = -1e30f;
                }
            }
        }

        float tm[4];
#pragma unroll
        for (int r = 0; r < 4; r++)
            tm[r] = fmaxf(fmaxf(s[0][r], s[1][r]), fmaxf(s[2][r], s[3][r]));
        bool rec = (tm[0] > m_run[0]) | (tm[1] > m_run[1]) |
                   (tm[2] > m_run[2]) | (tm[3] > m_run[3]);
        if (__any(rec)) {
#pragma unroll
            for (int r = 0; r < 4; r++) {
                float rm = tm[r];
#pragma unroll
                for (int off = 1; off < 16; off <<= 1) rm = fmaxf(rm, __shfl_xor(rm, off, 64));
                float mnew  = fmaxf(m_run[r], rm);
                float alpha = __builtin_amdgcn_exp2f(m_run[r] - mnew);
                m_run[r] = mnew;
                l_part[r] *= alpha;
#pragma unroll
                for (int dt = 0; dt < 4; dt++) o_acc[dt][r] *= alpha;
            }
        }

#pragma unroll
        for (int nt = 0; nt < 4; nt++) {
#pragma unroll
            for (int r = 0; r < 4; r++) {
                float p = __builtin_amdgcn_exp2f(s[nt][r] - m_run[r]);
                l_part[r] += p;
                Ps[wave * 16 * LDP + (quad * 4 + r) * LDP + nt * 16 + lane15] = (bf16)p;
            }
        }
        asm volatile("s_waitcnt lgkmcnt(0)" ::: "memory");
        __builtin_amdgcn_sched_barrier(0);
#pragma unroll
        for (int kk = 0; kk < 2; kk++) {
            bf16x8 pf = *(const bf16x8*)(&Ps[wave * 16 * LDP + lane15 * LDP + kk * 32 + quad * 8]);
#pragma unroll
            for (int dt = 0; dt < 4; dt++) {
                bf16x8 vf = *(const bf16x8*)(&Vs[cur][(dt * 2 + kk) * 512 + lane * 8]);
                o_acc[dt] = __builtin_amdgcn_mfma_f32_16x16x32_bf16(pf, vf, o_acc[dt], 0, 0, 0);
            }
        }
        if (kt + 1 < 24) {
            asm volatile("s_waitcnt vmcnt(0)" ::: "memory");
            __builtin_amdgcn_s_barrier();
            __builtin_amdgcn_sched_barrier(0);
        }
        cur ^= 1;
    }

    float l_inv[4];
#pragma unroll
    for (int r = 0; r < 4; r++) {
        float ls = l_part[r];
#pragma unroll
        for (int off = 1; off < 16; off <<= 1) ls += __shfl_xor(ls, off, 64);
        l_inv[r] = 1.0f / ls;
    }

#pragma unroll
    for (int dt = 0; dt < 4; dt++) {
#pragma unroll
        for (int r = 0; r < 4; r++) {
            int row = q0 + wave * 16 + quad * 4 + r;
            if (row < S) {
                float v = o_acc[dt][r] * l_inv[r];
                O[headoff + (size_t)row * C + dt * 16 + lane15] = (bf16)v;
            }
        }
    }
}

extern "C" void kernel_launch(void* const* d_in, const int* in_sizes, int n_in,
                              void* d_out, int out_size, void* d_ws, size_t ws_size,
                              hipStream_t stream) {
    float* out = (float*)d_out;
    const float* x_f32 = (const float*)d_in[0];
    const int M = 6000, Cc = 1024, F = 4096, Aa = 256;
    const size_t MC = (size_t)M * Cc;
    const size_t VT_ELEMS = (size_t)64 * 64 * 1536;
    bf16* ws = (bf16*)d_ws;

    bf16* h1   = ws;                         // [M,C]
    bf16* kbuf = ws + MC;                    // [M,C]
    bf16* Vt   = ws + 2 * MC;                // [64][64][1536]
    bf16* g    = ws + 2 * MC + VT_ELEMS;     // [M,F]
    bf16* q    = (bf16*)d_out;               // d_out spare half as bf16 scratch
    bf16* wv   = h1;
    bf16* x1   = q;
    bf16* h2   = kbuf;
    bf16* x2   = Vt;
    bf16* aact = kbuf;
    // split-K partial buffers (regions dead at time of use; stream-ordered):
    bf16* P0o  = kbuf;                       // Wo partials: kbuf free (attn done)
    bf16* P1o  = g;                          //              g free (W1 not yet)
    bf16* P0   = kbuf;                       // W2 partials: h2 consumed by W1
    bf16* P1   = h1;                         //              wv consumed by Wo
    bf16* P0d  = h1;                         // Wds partials: P1 consumed
    bf16* P1d  = h1 + (size_t)M * Aa;
    bf16* P0u  = g;                          // Wus partials: g consumed by W2
    bf16* P1u  = g + MC;

    size_t off = 2 * MC + VT_ELEMS + (size_t)M * F;
    bf16* Wqkv = ws + off; off += (size_t)3 * 1024 * 1024;
    bf16* bqkv = ws + off; off += 3072;
    bf16* sWo  = ws + off; off += (size_t)1024 * 1024;
    bf16* sbo  = ws + off; off += 1024;
    bf16* slnw = ws + off; off += 1024;
    bf16* slnb = ws + off; off += 1024;
    bf16* sW1  = ws + off; off += (size_t)4096 * 1024;
    bf16* sb1  = ws + off; off += 4096;
    bf16* sW2  = ws + off; off += (size_t)1024 * 4096;
    bf16* sb2  = ws + off; off += 1024;
    bf16* sln2w = ws + off; off += 1024;
    bf16* sln2b = ws + off; off += 1024;
    bf16* sWds = ws + off; off += (size_t)256 * 1024;
    bf16* sbds = ws + off; off += 256;
    bf16* sWus = ws + off; off += (size_t)1024 * 256;
    bf16* sbus = ws + off; off += 1024;

    ConvArgs ca;
    const int srcidx[19] = {1, 3, 4, 2, 5, 6, 7, 8, 9, 10, 11, 12, 13, 14, 15, 16, 17, 18, 19};
    bf16* dsts[19] = {Wqkv, Wqkv + 1048576, Wqkv + 2097152, bqkv, bqkv + 2048,
                      sWo, sbo, slnw, slnb, sW1, sb1, sW2, sb2, sln2w, sln2b,
                      sWds, sbds, sWus, sbus};
    int bacc = 0;
    for (int i = 0; i < 19; i++) {
        ca.src[i] = (const float*)d_in[srcidx[i]];
        ca.dst[i] = dsts[i];
        ca.n[i] = in_sizes[srcidx[i]];
        ca.bstart[i] = bacc;
        bacc += (ca.n[i] + 2047) / 2048;
    }
    ca.bstart[19] = bacc;

    dim3 blk(256);
    convert_many<<<bacc, blk, 0, stream>>>(ca);
    zero_kernel<<<4, blk, 0, stream>>>(bqkv + 1024, 1024);   // no k-bias

    const float scale = 0.35355339059327373f;  // 64^-0.25
    const int gmT = 47, mQ = 12;               // ceil(47/4)
    auto grid_for = [&](int gnT) { int nQ = (gnT + 1) >> 1; return dim3(8 * mQ * nQ); };

    ln_kernel<float><<<M, blk, 0, stream>>>(x_f32, slnw, slnb, h1);
    // QKV: BK=128, 8 K-steps
    gemm_kernel<0, 2, 4, bf16, bf16><<<grid_for(24), blk, 0, stream>>>(
        h1, Wqkv, bqkv, (const bf16*)nullptr, q, kbuf, Vt, M, 3072, Cc, scale, gmT, 24, mQ, Cc);
    dim3 ga(24, 64);
    flash_attn_kernel<<<ga, blk, 0, stream>>>(q, kbuf, Vt, wv);

    // Wo: split-K=2 (K=512/block, BK=128 -> 4 steps), reduce adds bo + float x resid
    {
        dim3 gr = grid_for(8); gr.y = 2;
        gemm_kernel<0, 3, 4, bf16, bf16><<<gr, blk, 0, stream>>>(
            wv, sWo, nullptr, (const bf16*)nullptr, P0o, P1o, nullptr,
            M, Cc, Cc / 2, 1.0f, gmT, 8, mQ, Cc);
        reduce_kernel<0, 1, float, bf16><<<(M * Cc) / 2048, blk, 0, stream>>>(
            P0o, P1o, sbo, x_f32, x1, Cc - 1, M * Cc);
    }

    ln_kernel<bf16><<<M, blk, 0, stream>>>(x1, sln2w, sln2b, h2);
    // W1: BK=128, 8 K-steps
    gemm_kernel<1, 0, 4, bf16, bf16><<<grid_for(32), blk, 0, stream>>>(
        h2, sW1, sb1, (const bf16*)nullptr, g, nullptr, nullptr, M, F, Cc, 1.0f, gmT, 32, mQ, Cc);

    // W2: split-K=2 (K=2048/block, BK=128 -> 16 steps), reduce adds b2 + x1 resid
    {
        dim3 gr = grid_for(8); gr.y = 2;
        gemm_kernel<0, 3, 4, bf16, bf16><<<gr, blk, 0, stream>>>(
            g, sW2, nullptr, (const bf16*)nullptr, P0, P1, nullptr,
            M, Cc, F / 2, 1.0f, gmT, 8, mQ, F);
        reduce_kernel<0, 1, bf16, bf16><<<(M * Cc) / 2048, blk, 0, stream>>>(
            P0, P1, sb2, x1, x2, Cc - 1, M * Cc);
    }

    // adapter down (Wds): split-K=2 (K=512, BK=128 -> 4 steps), gelu-reduce
    {
        dim3 gr = grid_for(2); gr.y = 2;
        gemm_kernel<0, 3, 4, bf16, bf16><<<gr, blk, 0, stream>>>(
            x2, sWds, nullptr, (const bf16*)nullptr, P0d, P1d, nullptr,
            M, Aa, Cc / 2, 1.0f, gmT, 2, mQ, Cc);
        reduce_kernel<1, 0, bf16, bf16><<<(M * Aa) / 2048, blk, 0, stream>>>(
            P0d, P1d, sbds, nullptr, aact, Aa - 1, M * Aa);
    }

    // adapter up (Wus): split-K=2 (K=128/block, BK=128 -> 1 step), reduce adds bus + x2, float out
    {
        dim3 gr = grid_for(8); gr.y = 2;
        gemm_kernel<0, 3, 4, bf16, bf16><<<gr, blk, 0, stream>>>(
            aact, sWus, nullptr, (const bf16*)nullptr, P0u, P1u, nullptr,
            M, Cc, Aa / 2, 1.0f, gmT, 8, mQ, Aa);
        reduce_kernel<0, 1, bf16, float><<<(M * Cc) / 2048, blk, 0, stream>>>(
            P0u, P1u, sbus, x2, out, Cc - 1, M * Cc);
    }
}

// Round 9
// 690.378 us; speedup vs baseline: 1.6665x; 1.0872x over previous
//
#include <hip/hip_runtime.h>
#include <hip/hip_bf16.h>
#include <math.h>

typedef __bf16 bf16;
typedef __bf16 bf16x8 __attribute__((ext_vector_type(8)));
typedef float  f32x4  __attribute__((ext_vector_type(4)));

// async global->LDS, 16 B per lane; LDS dest = wave-uniform base + lane*16
__device__ __forceinline__ void load16_lds(const bf16* g, bf16* l) {
    __builtin_amdgcn_global_load_lds(
        (__attribute__((address_space(1))) void*)(g),
        (__attribute__((address_space(3))) void*)(l), 16, 0, 0);
}

// tanh-form GELU (max abs err vs exact erf-GELU ~7e-4)
__device__ __forceinline__ float gelu_f(float x) {
    float u = 1.5957691216057308f * (x + 0.044715f * x * x * x);  // 2*sqrt(2/pi)*(...)
    float e = __expf(u);
    float th = 1.0f - 2.0f / (1.0f + e);
    return 0.5f * x * (1.0f + th);
}

// ---------------- fused weight converts ----------------
struct ConvArgs {
    const float* src[19];
    bf16* dst[19];
    int n[19];
    int bstart[20];
};
__global__ __launch_bounds__(256) void convert_many(ConvArgs a) {
    int blk = blockIdx.x;
    int s = 0;
    while (blk >= a.bstart[s + 1]) s++;
    const float* src = a.src[s];
    bf16* dst = a.dst[s];
    int n = a.n[s];
    int i0 = (blk - a.bstart[s]) * 2048;
#pragma unroll
    for (int e = 0; e < 8; e++) {
        int i = i0 + threadIdx.x + e * 256;
        if (i < n) dst[i] = (bf16)src[i];
    }
}

__global__ void zero_kernel(bf16* dst, int n) {
    int i = blockIdx.x * blockDim.x + threadIdx.x;
    if (i < n) dst[i] = (bf16)0.0f;
}

// ---------------- split-K reduce: out = [gelu](P0+P1+bias) [+resid] ----------------
template<int ACT, int RES, class RT, class OT>
__global__ __launch_bounds__(256) void reduce_kernel(
    const bf16* __restrict__ P0, const bf16* __restrict__ P1,
    const bf16* __restrict__ bias, const RT* __restrict__ resid,
    OT* __restrict__ out, int nmask, int total)
{
    int i = (blockIdx.x * 256 + threadIdx.x) * 8;
    if (i >= total) return;
    bf16x8 p0 = *(const bf16x8*)(P0 + i);
    bf16x8 p1 = *(const bf16x8*)(P1 + i);
    bf16x8 bb = *(const bf16x8*)(bias + (i & nmask));
#pragma unroll
    for (int j = 0; j < 8; j++) {
        float v = (float)p0[j] + (float)p1[j] + (float)bb[j];
        if (ACT) v = gelu_f(v);
        if (RES) v += (float)resid[i + j];
        out[i + j] = (OT)v;
    }
}

// ---------------- fused Wo-reduce + LayerNorm ----------------
// x1 = P0+P1+bo+xres (written out); h2 = LN(x1)*w+b. One row per block.
// In-place safe vs P0/P1 aliasing: each thread writes only elements it read,
// and all P0/P1 reads precede the block barrier while h2 writes follow it.
__global__ __launch_bounds__(256) void reduce_ln_kernel(
    const bf16* __restrict__ P0, const bf16* __restrict__ P1,
    const bf16* __restrict__ bo, const float* __restrict__ xres,
    bf16* __restrict__ x1, const bf16* __restrict__ w,
    const bf16* __restrict__ b, bf16* __restrict__ h2)
{
    const int C = 1024;
    const int row = blockIdx.x;
    const int tid = threadIdx.x;
    const size_t base = (size_t)row * C + tid * 4;
    float v[4];
#pragma unroll
    for (int j = 0; j < 4; j++) {
        v[j] = (float)P0[base + j] + (float)P1[base + j]
             + (float)bo[tid * 4 + j] + xres[base + j];
    }
    // write x1 (bf16) -- the residual stream value
    bf16* xo = x1 + base;
#pragma unroll
    for (int j = 0; j < 4; j++) xo[j] = (bf16)v[j];
    // LN uses the bf16-rounded values (matches separate-kernel behavior)
    float q0 = (float)xo[0], q1 = (float)xo[1], q2 = (float)xo[2], q3 = (float)xo[3];
    float s  = q0 + q1 + q2 + q3;
    float sq = q0*q0 + q1*q1 + q2*q2 + q3*q3;
#pragma unroll
    for (int off = 32; off >= 1; off >>= 1) {
        s  += __shfl_xor(s,  off, 64);
        sq += __shfl_xor(sq, off, 64);
    }
    __shared__ float red[8];
    int wave = tid >> 6;
    if ((tid & 63) == 0) { red[wave] = s; red[4 + wave] = sq; }
    __syncthreads();
    float ts = red[0] + red[1] + red[2] + red[3];
    float tq = red[4] + red[5] + red[6] + red[7];
    float mean = ts * (1.0f / C);
    float var  = tq * (1.0f / C) - mean * mean;
    float rstd = rsqrtf(var + 1e-5f);
    bf16* orow = h2 + base;
#pragma unroll
    for (int j = 0; j < 4; j++) {
        float wj = (float)w[tid * 4 + j], bj = (float)b[tid * 4 + j];
        float qj = (j == 0 ? q0 : j == 1 ? q1 : j == 2 ? q2 : q3);
        orow[j] = (bf16)((qj - mean) * rstd * wj + bj);
    }
}

// ---------------- LayerNorm ----------------
template<class XT>
__global__ __launch_bounds__(256) void ln_kernel(
    const XT* __restrict__ X, const bf16* __restrict__ w,
    const bf16* __restrict__ b, bf16* __restrict__ out)
{
    const int C = 1024;
    const int row = blockIdx.x;
    const int tid = threadIdx.x;
    const XT* xr = X + (size_t)row * C;
    float x0 = (float)xr[tid * 4 + 0], x1 = (float)xr[tid * 4 + 1];
    float x2 = (float)xr[tid * 4 + 2], x3 = (float)xr[tid * 4 + 3];
    float s  = x0 + x1 + x2 + x3;
    float sq = x0*x0 + x1*x1 + x2*x2 + x3*x3;
#pragma unroll
    for (int off = 32; off >= 1; off >>= 1) {
        s  += __shfl_xor(s,  off, 64);
        sq += __shfl_xor(sq, off, 64);
    }
    __shared__ float red[8];
    int wave = tid >> 6;
    if ((tid & 63) == 0) { red[wave] = s; red[4 + wave] = sq; }
    __syncthreads();
    float ts = red[0] + red[1] + red[2] + red[3];
    float tq = red[4] + red[5] + red[6] + red[7];
    float mean = ts * (1.0f / C);
    float var  = tq * (1.0f / C) - mean * mean;
    float rstd = rsqrtf(var + 1e-5f);
    float w0 = (float)w[tid*4+0], w1 = (float)w[tid*4+1], w2 = (float)w[tid*4+2], w3 = (float)w[tid*4+3];
    float b0 = (float)b[tid*4+0], b1 = (float)b[tid*4+1], b2 = (float)b[tid*4+2], b3 = (float)b[tid*4+3];
    bf16* orow = out + (size_t)row * C + tid * 4;
    orow[0] = (bf16)((x0 - mean) * rstd * w0 + b0);
    orow[1] = (bf16)((x1 - mean) * rstd * w1 + b1);
    orow[2] = (bf16)((x2 - mean) * rstd * w2 + b2);
    orow[3] = (bf16)((x3 - mean) * rstd * w3 + b3);
}

// ---------------- GEMM 128x128, BK=64 (single-buffer r1 structure; proven) ----------------
// OMODE 0: normal; 2: fused QKV split; 3: split-K partial (blockIdx.y selects
//          K-half and output buffer). ldK = row stride (full K); K = block's K extent.
template<int ACT, int OMODE, class RT, class OT>
__global__ __launch_bounds__(256) void gemm_kernel(
    const bf16* __restrict__ A, const bf16* __restrict__ W,
    const bf16* __restrict__ bias, const RT* __restrict__ resid,
    OT* __restrict__ out, bf16* __restrict__ out_k, bf16* __restrict__ out_v,
    int M, int N, int K, float scale, int gmT, int gnT, int mQ, int ldK)
{
    const int lin = blockIdx.x;
    const int xcd = lin & 7;
    const int t_  = lin >> 3;
    const int mt_ = (xcd & 3) + 4 * (t_ % mQ);
    const int nt_ = (xcd >> 2) + 2 * (t_ / mQ);
    if (mt_ >= gmT || nt_ >= gnT) return;
    const int m0 = mt_ * 128;
    const int n0 = nt_ * 128;
    const int ksp = (OMODE == 3) ? blockIdx.y : 0;
    const size_t ko = (size_t)ksp * K;

    __shared__ __align__(16) bf16 As[16 * 512];
    __shared__ __align__(16) bf16 Bs[16 * 512];
    const int tid = threadIdx.x;
    const int wave = tid >> 6, lane = tid & 63;
    const int lane15 = lane & 15, quad = lane >> 4;
    const int wm0 = (wave >> 1) * 64;
    const int wn0 = (wave & 1) * 64;
    f32x4 acc[4][4] = {};

    int ra0 = m0 + (2 * wave)     * 16 + lane15; if (ra0 > M - 1) ra0 = M - 1;
    int ra1 = m0 + (2 * wave + 1) * 16 + lane15; if (ra1 > M - 1) ra1 = M - 1;
    const int rb0 = n0 + (2 * wave)     * 16 + lane15;
    const int rb1 = n0 + (2 * wave + 1) * 16 + lane15;
    const bf16* a0 = A + (size_t)ra0 * ldK + ko + quad * 8;
    const bf16* a1 = A + (size_t)ra1 * ldK + ko + quad * 8;
    const bf16* w0 = W + (size_t)rb0 * ldK + ko + quad * 8;
    const bf16* w1 = W + (size_t)rb1 * ldK + ko + quad * 8;

    for (int k0 = 0; k0 < K; k0 += 64) {
#pragma unroll
        for (int kk = 0; kk < 2; kk++) {
            load16_lds(a0 + k0 + kk * 32, &As[((2 * wave)     * 2 + kk) * 512]);
            load16_lds(a1 + k0 + kk * 32, &As[((2 * wave + 1) * 2 + kk) * 512]);
            load16_lds(w0 + k0 + kk * 32, &Bs[((2 * wave)     * 2 + kk) * 512]);
            load16_lds(w1 + k0 + kk * 32, &Bs[((2 * wave + 1) * 2 + kk) * 512]);
        }
        __syncthreads();
#pragma unroll
        for (int kk = 0; kk < 2; kk++) {
            bf16x8 af[4], bfr[4];
#pragma unroll
            for (int tt = 0; tt < 4; tt++) {
                af[tt]  = *(const bf16x8*)(&As[(((wm0 >> 4) + tt) * 2 + kk) * 512 + lane * 8]);
                bfr[tt] = *(const bf16x8*)(&Bs[(((wn0 >> 4) + tt) * 2 + kk) * 512 + lane * 8]);
            }
#pragma unroll
            for (int mt = 0; mt < 4; mt++)
#pragma unroll
                for (int nt = 0; nt < 4; nt++)
                    acc[mt][nt] = __builtin_amdgcn_mfma_f32_16x16x32_bf16(
                        af[mt], bfr[nt], acc[mt][nt], 0, 0, 0);
        }
        __syncthreads();
    }

#pragma unroll
    for (int mt = 0; mt < 4; mt++) {
#pragma unroll
        for (int r = 0; r < 4; r++) {
            int gm = m0 + wm0 + mt * 16 + quad * 4 + r;
            if (gm >= M) continue;
#pragma unroll
            for (int nt = 0; nt < 4; nt++) {
                int gn = n0 + wn0 + nt * 16 + lane15;
                float v = acc[mt][nt][r];
                if (OMODE == 3) {
                    bf16* po = ksp ? out_k : (bf16*)out;
                    po[(size_t)gm * N + gn] = (bf16)v;
                    continue;
                }
                if (bias) v += (float)bias[gn];
                if (OMODE == 2) {
                    if (gn < 2048) {
                        v *= scale;
                        if (gn < 1024) v *= 1.4426950408889634f;  // exp2-domain softmax
                    }
                } else v *= scale;
                if (ACT == 1) v = gelu_f(v);
                if (OMODE == 2) {
                    if (gn < 1024) {
                        ((bf16*)out)[(size_t)gm * 1024 + gn] = (bf16)v;            // q
                    } else if (gn < 2048) {
                        out_k[(size_t)gm * 1024 + (gn - 1024)] = (bf16)v;          // k
                    } else {
                        int gg = gn - 2048;
                        int bb = gm / 1500;
                        int ss = gm - bb * 1500;
                        int hh = gg >> 6, dd = gg & 63;
                        out_v[(((size_t)bb * 16 + hh) * 64 + dd) * 1536 + ss] = (bf16)v;  // v^T
                    }
                } else {
                    if (resid) v += (float)resid[(size_t)gm * N + gn];
                    out[(size_t)gm * N + gn] = (OT)v;
                }
            }
        }
    }
}

// ---------------- GEMM 256x128 wide-tile (8 waves, BK=64, single-buffer) ----------------
// Staged bytes per output: (256+128)*K*2B per 32768 outputs = 1.5x better than 128^2.
// Identical staging/read/epilogue formulas to gemm_kernel; only the wave grid
// (4Mx2N) and B-staging (1 row-group per wave) differ. LDS 48 KB -> 3 blocks/CU.
template<int ACT, class OT>
__global__ __launch_bounds__(512) void gemm_wide_kernel(
    const bf16* __restrict__ A, const bf16* __restrict__ W,
    const bf16* __restrict__ bias, OT* __restrict__ out,
    int M, int N, int K, int gmT, int gnT, int mQ, int ldK)
{
    const int lin = blockIdx.x;
    const int xcd = lin & 7;
    const int t_  = lin >> 3;
    const int mt_ = (xcd & 3) + 4 * (t_ % mQ);
    const int nt_ = (xcd >> 2) + 2 * (t_ / mQ);
    if (mt_ >= gmT || nt_ >= gnT) return;
    const int m0 = mt_ * 256;
    const int n0 = nt_ * 128;

    __shared__ __align__(16) bf16 As[32 * 512];   // 16 row-groups x 2 kk
    __shared__ __align__(16) bf16 Bs[16 * 512];   // 8 row-groups x 2 kk
    const int tid = threadIdx.x;
    const int wave = tid >> 6, lane = tid & 63;
    const int lane15 = lane & 15, quad = lane >> 4;
    const int wm0 = (wave >> 1) * 64;   // 4 wave-rows: 0,64,128,192
    const int wn0 = (wave & 1) * 64;    // 2 wave-cols: 0,64
    f32x4 acc[4][4] = {};

    int ra0 = m0 + (2 * wave)     * 16 + lane15; if (ra0 > M - 1) ra0 = M - 1;
    int ra1 = m0 + (2 * wave + 1) * 16 + lane15; if (ra1 > M - 1) ra1 = M - 1;
    const int rb = n0 + wave * 16 + lane15;      // 8 waves cover 128 B-rows
    const bf16* a0 = A + (size_t)ra0 * ldK + quad * 8;
    const bf16* a1 = A + (size_t)ra1 * ldK + quad * 8;
    const bf16* w0 = W + (size_t)rb * ldK + quad * 8;

    for (int k0 = 0; k0 < K; k0 += 64) {
#pragma unroll
        for (int kk = 0; kk < 2; kk++) {
            load16_lds(a0 + k0 + kk * 32, &As[((2 * wave)     * 2 + kk) * 512]);
            load16_lds(a1 + k0 + kk * 32, &As[((2 * wave + 1) * 2 + kk) * 512]);
            load16_lds(w0 + k0 + kk * 32, &Bs[(wave * 2 + kk) * 512]);
        }
        __syncthreads();
#pragma unroll
        for (int kk = 0; kk < 2; kk++) {
            bf16x8 af[4], bfr[4];
#pragma unroll
            for (int tt = 0; tt < 4; tt++) {
                af[tt]  = *(const bf16x8*)(&As[(((wm0 >> 4) + tt) * 2 + kk) * 512 + lane * 8]);
                bfr[tt] = *(const bf16x8*)(&Bs[(((wn0 >> 4) + tt) * 2 + kk) * 512 + lane * 8]);
            }
#pragma unroll
            for (int mt = 0; mt < 4; mt++)
#pragma unroll
                for (int nt = 0; nt < 4; nt++)
                    acc[mt][nt] = __builtin_amdgcn_mfma_f32_16x16x32_bf16(
                        af[mt], bfr[nt], acc[mt][nt], 0, 0, 0);
        }
        __syncthreads();
    }

#pragma unroll
    for (int mt = 0; mt < 4; mt++) {
#pragma unroll
        for (int r = 0; r < 4; r++) {
            int gm = m0 + wm0 + mt * 16 + quad * 4 + r;
            if (gm >= M) continue;
#pragma unroll
            for (int nt = 0; nt < 4; nt++) {
                int gn = n0 + wn0 + nt * 16 + lane15;
                float v = acc[mt][nt][r] + (float)bias[gn];
                if (ACT == 1) v = gelu_f(v);
                out[(size_t)gm * N + gn] = (OT)v;
            }
        }
    }
}

// ---------------- Flash attention (2-phase double-buffered K/V) ----------------
__global__ __launch_bounds__(256) void flash_attn_kernel(
    const bf16* __restrict__ Q, const bf16* __restrict__ Km,
    const bf16* __restrict__ Vt, bf16* __restrict__ O)
{
    const int S = 1500, C = 1024, SP = 1536;
    const int LDP = 72;
    __shared__ __align__(16) bf16 Ks[2][8 * 512];
    __shared__ __align__(16) bf16 Vs[2][8 * 512];
    __shared__ __align__(16) bf16 Ps[4 * 16 * LDP];
    const int tid = threadIdx.x;
    const int wave = tid >> 6, lane = tid & 63;
    const int lane15 = lane & 15, quad = lane >> 4;
    const int bh = blockIdx.y;
    const int q0 = blockIdx.x * 64;
    const size_t headoff = (size_t)(bh >> 4) * S * C + (size_t)(bh & 15) * 64;
    const size_t vtoff   = (size_t)bh * 64 * SP;

    bf16x8 qf[2];
    int qr = q0 + wave * 16 + lane15; if (qr > S - 1) qr = S - 1;
    qf[0] = *(const bf16x8*)(Q + headoff + (size_t)qr * C + quad * 8);
    qf[1] = *(const bf16x8*)(Q + headoff + (size_t)qr * C + 32 + quad * 8);

    const bf16* vbase = Vt + vtoff + (size_t)(wave * 16 + lane15) * SP + quad * 8;

    auto stageKV = [&](int buf, int kt) {
        const int j0 = kt * 64;
        int kr = j0 + wave * 16 + lane15; if (kr > S - 1) kr = S - 1;
        const bf16* kbase = Km + headoff + (size_t)kr * C + quad * 8;
#pragma unroll
        for (int kk = 0; kk < 2; kk++) {
            load16_lds(kbase + kk * 32,      &Ks[buf][(wave * 2 + kk) * 512]);
            load16_lds(vbase + j0 + kk * 32, &Vs[buf][(wave * 2 + kk) * 512]);
        }
    };

    float m_run[4], l_part[4];
    f32x4 o_acc[4] = {};
#pragma unroll
    for (int r = 0; r < 4; r++) { m_run[r] = 4.0f; l_part[r] = 0.0f; }

    stageKV(0, 0);
    asm volatile("s_waitcnt vmcnt(0)" ::: "memory");
    __builtin_amdgcn_s_barrier();
    __builtin_amdgcn_sched_barrier(0);

    int cur = 0;
    for (int kt = 0; kt < 24; kt++) {
        if (kt + 1 < 24) stageKV(cur ^ 1, kt + 1);
        const int j0 = kt * 64;

        f32x4 s[4] = {};
#pragma unroll
        for (int kk = 0; kk < 2; kk++) {
#pragma unroll
            for (int nt = 0; nt < 4; nt++) {
                bf16x8 kf = *(const bf16x8*)(&Ks[cur][(nt * 2 + kk) * 512 + lane * 8]);
                s[nt] = __builtin_amdgcn_mfma_f32_16x16x32_bf16(qf[kk], kf, s[nt], 0, 0, 0);
            }
        }
        if (kt == 23) {
#pragma unroll
            for (int nt = 0; nt < 4; nt++) {
                if (j0 + nt * 16 + lane15 >= S) {
#pragma unroll
                    for (int r = 0; r < 4; r++) s[nt][r] = -1e30f;
                }
            }
        }

        float tm[4];
#pragma unroll
        for (int r = 0; r < 4; r++)
            tm[r] = fmaxf(fmaxf(s[0][r], s[1][r]), fmaxf(s[2][r], s[3][r]));
        bool rec = (tm[0] > m_run[0]) | (tm[1] > m_run[1]) |
                   (tm[2] > m_run[2]) | (tm[3] > m_run[3]);
        if (__any(rec)) {
#pragma unroll
            for (int r = 0; r < 4; r++) {
                float rm = tm[r];
#pragma unroll
                for (int off = 1; off < 16; off <<= 1) rm = fmaxf(rm, __shfl_xor(rm, off, 64));
                float mnew  = fmaxf(m_run[r], rm);
                float alpha = __builtin_amdgcn_exp2f(m_run[r] - mnew);
                m_run[r] = mnew;
                l_part[r] *= alpha;
#pragma unroll
                for (int dt = 0; dt < 4; dt++) o_acc[dt][r] *= alpha;
            }
        }

#pragma unroll
        for (int nt = 0; nt < 4; nt++) {
#pragma unroll
            for (int r = 0; r < 4; r++) {
                float p = __builtin_amdgcn_exp2f(s[nt][r] - m_run[r]);
                l_part[r] += p;
                Ps[wave * 16 * LDP + (quad * 4 + r) * LDP + nt * 16 + lane15] = (bf16)p;
            }
        }
        asm volatile("s_waitcnt lgkmcnt(0)" ::: "memory");
        __builtin_amdgcn_sched_barrier(0);
#pragma unroll
        for (int kk = 0; kk < 2; kk++) {
            bf16x8 pf = *(const bf16x8*)(&Ps[wave * 16 * LDP + lane15 * LDP + kk * 32 + quad * 8]);
#pragma unroll
            for (int dt = 0; dt < 4; dt++) {
                bf16x8 vf = *(const bf16x8*)(&Vs[cur][(dt * 2 + kk) * 512 + lane * 8]);
                o_acc[dt] = __builtin_amdgcn_mfma_f32_16x16x32_bf16(pf, vf, o_acc[dt], 0, 0, 0);
            }
        }
        if (kt + 1 < 24) {
            asm volatile("s_waitcnt vmcnt(0)" ::: "memory");
            __builtin_amdgcn_s_barrier();
            __builtin_amdgcn_sched_barrier(0);
        }
        cur ^= 1;
    }

    float l_inv[4];
#pragma unroll
    for (int r = 0; r < 4; r++) {
        float ls = l_part[r];
#pragma unroll
        for (int off = 1; off < 16; off <<= 1) ls += __shfl_xor(ls, off, 64);
        l_inv[r] = 1.0f / ls;
    }

#pragma unroll
    for (int dt = 0; dt < 4; dt++) {
#pragma unroll
        for (int r = 0; r < 4; r++) {
            int row = q0 + wave * 16 + quad * 4 + r;
            if (row < S) {
                float v = o_acc[dt][r] * l_inv[r];
                O[headoff + (size_t)row * C + dt * 16 + lane15] = (bf16)v;
            }
        }
    }
}

extern "C" void kernel_launch(void* const* d_in, const int* in_sizes, int n_in,
                              void* d_out, int out_size, void* d_ws, size_t ws_size,
                              hipStream_t stream) {
    float* out = (float*)d_out;
    const float* x_f32 = (const float*)d_in[0];
    const int M = 6000, Cc = 1024, F = 4096, Aa = 256;
    const size_t MC = (size_t)M * Cc;
    const size_t VT_ELEMS = (size_t)64 * 64 * 1536;
    bf16* ws = (bf16*)d_ws;

    bf16* h1   = ws;                         // [M,C]
    bf16* kbuf = ws + MC;                    // [M,C]
    bf16* Vt   = ws + 2 * MC;                // [64][64][1536]
    bf16* g    = ws + 2 * MC + VT_ELEMS;     // [M,F]
    bf16* q    = (bf16*)d_out;               // d_out spare half as bf16 scratch
    bf16* wv   = h1;
    bf16* x1   = q;
    bf16* h2   = kbuf;
    bf16* x2   = Vt;
    bf16* aact = kbuf;
    // split-K partial buffers (regions dead at time of use; stream-ordered):
    bf16* P0o  = kbuf;                       // Wo partials: kbuf free (attn done)
    bf16* P1o  = g;                          //              g free (W1 not yet)
    bf16* P0   = kbuf;                       // W2 partials: h2 consumed by W1
    bf16* P1   = h1;                         //              wv consumed by Wo
    bf16* P0d  = h1;                         // Wds partials: P1 consumed
    bf16* P1d  = h1 + (size_t)M * Aa;
    bf16* P0u  = g;                          // Wus partials: g consumed by W2
    bf16* P1u  = g + MC;

    size_t off = 2 * MC + VT_ELEMS + (size_t)M * F;
    bf16* Wqkv = ws + off; off += (size_t)3 * 1024 * 1024;
    bf16* bqkv = ws + off; off += 3072;
    bf16* sWo  = ws + off; off += (size_t)1024 * 1024;
    bf16* sbo  = ws + off; off += 1024;
    bf16* slnw = ws + off; off += 1024;
    bf16* slnb = ws + off; off += 1024;
    bf16* sW1  = ws + off; off += (size_t)4096 * 1024;
    bf16* sb1  = ws + off; off += 4096;
    bf16* sW2  = ws + off; off += (size_t)1024 * 4096;
    bf16* sb2  = ws + off; off += 1024;
    bf16* sln2w = ws + off; off += 1024;
    bf16* sln2b = ws + off; off += 1024;
    bf16* sWds = ws + off; off += (size_t)256 * 1024;
    bf16* sbds = ws + off; off += 256;
    bf16* sWus = ws + off; off += (size_t)1024 * 256;
    bf16* sbus = ws + off; off += 1024;

    ConvArgs ca;
    const int srcidx[19] = {1, 3, 4, 2, 5, 6, 7, 8, 9, 10, 11, 12, 13, 14, 15, 16, 17, 18, 19};
    bf16* dsts[19] = {Wqkv, Wqkv + 1048576, Wqkv + 2097152, bqkv, bqkv + 2048,
                      sWo, sbo, slnw, slnb, sW1, sb1, sW2, sb2, sln2w, sln2b,
                      sWds, sbds, sWus, sbus};
    int bacc = 0;
    for (int i = 0; i < 19; i++) {
        ca.src[i] = (const float*)d_in[srcidx[i]];
        ca.dst[i] = dsts[i];
        ca.n[i] = in_sizes[srcidx[i]];
        ca.bstart[i] = bacc;
        bacc += (ca.n[i] + 2047) / 2048;
    }
    ca.bstart[19] = bacc;

    dim3 blk(256);
    dim3 blk512(512);
    convert_many<<<bacc, blk, 0, stream>>>(ca);
    zero_kernel<<<4, blk, 0, stream>>>(bqkv + 1024, 1024);   // no k-bias

    const float scale = 0.35355339059327373f;  // 64^-0.25
    const int gmT = 47, mQ = 12;               // 128-row tiles
    auto grid_for = [&](int gnT) { int nQ = (gnT + 1) >> 1; return dim3(8 * mQ * nQ); };
    const int gmTw = 24, mQw = 6;              // 256-row tiles (wide kernel)
    auto gridw_for = [&](int gnT) { int nQ = (gnT + 1) >> 1; return dim3(8 * mQw * nQ); };

    ln_kernel<float><<<M, blk, 0, stream>>>(x_f32, slnw, slnb, h1);
    // QKV: proven 128^2 BK=64
    gemm_kernel<0, 2, bf16, bf16><<<grid_for(24), blk, 0, stream>>>(
        h1, Wqkv, bqkv, (const bf16*)nullptr, q, kbuf, Vt, M, 3072, Cc, scale, gmT, 24, mQ, Cc);
    dim3 ga(24, 64);
    flash_attn_kernel<<<ga, blk, 0, stream>>>(q, kbuf, Vt, wv);

    // Wo: split-K=2, then fused reduce+LN (x1 and h2 in one pass)
    {
        dim3 gr = grid_for(8); gr.y = 2;
        gemm_kernel<0, 3, bf16, bf16><<<gr, blk, 0, stream>>>(
            wv, sWo, nullptr, (const bf16*)nullptr, P0o, P1o, nullptr,
            M, Cc, Cc / 2, 1.0f, gmT, 8, mQ, Cc);
        reduce_ln_kernel<<<M, blk, 0, stream>>>(
            P0o, P1o, sbo, x_f32, x1, sln2w, sln2b, h2);
    }

    // W1: 256x128 wide tile (experiment: 25% fewer staged bytes/output)
    gemm_wide_kernel<1, bf16><<<gridw_for(32), blk512, 0, stream>>>(
        h2, sW1, sb1, g, M, F, Cc, gmTw, 32, mQw, Cc);

    // W2: split-K=2, reduce adds b2 + x1 resid
    {
        dim3 gr = grid_for(8); gr.y = 2;
        gemm_kernel<0, 3, bf16, bf16><<<gr, blk, 0, stream>>>(
            g, sW2, nullptr, (const bf16*)nullptr, P0, P1, nullptr,
            M, Cc, F / 2, 1.0f, gmT, 8, mQ, F);
        reduce_kernel<0, 1, bf16, bf16><<<(M * Cc) / 2048, blk, 0, stream>>>(
            P0, P1, sb2, x1, x2, Cc - 1, M * Cc);
    }

    // adapter down (Wds): split-K=2, gelu-reduce
    {
        dim3 gr = grid_for(2); gr.y = 2;
        gemm_kernel<0, 3, bf16, bf16><<<gr, blk, 0, stream>>>(
            x2, sWds, nullptr, (const bf16*)nullptr, P0d, P1d, nullptr,
            M, Aa, Cc / 2, 1.0f, gmT, 2, mQ, Cc);
        reduce_kernel<1, 0, bf16, bf16><<<(M * Aa) / 2048, blk, 0, stream>>>(
            P0d, P1d, sbds, nullptr, aact, Aa - 1, M * Aa);
    }

    // adapter up (Wus): split-K=2, reduce adds bus + x2, float out
    {
        dim3 gr = grid_for(8); gr.y = 2;
        gemm_kernel<0, 3, bf16, bf16><<<gr, blk, 0, stream>>>(
            aact, sWus, nullptr, (const bf16*)nullptr, P0u, P1u, nullptr,
            M, Cc, Aa / 2, 1.0f, gmT, 8, mQ, Aa);
        reduce_kernel<0, 1, bf16, float><<<(M * Cc) / 2048, blk, 0, stream>>>(
            P0u, P1u, sbus, x2, out, Cc - 1, M * Cc);
    }
}

// Round 10
// 681.105 us; speedup vs baseline: 1.6892x; 1.0136x over previous
//
#include <hip/hip_runtime.h>
#include <hip/hip_bf16.h>
#include <math.h>

typedef __bf16 bf16;
typedef __bf16 bf16x8 __attribute__((ext_vector_type(8)));
typedef float  f32x4  __attribute__((ext_vector_type(4)));

// async global->LDS, 16 B per lane; LDS dest = wave-uniform base + lane*16
__device__ __forceinline__ void load16_lds(const bf16* g, bf16* l) {
    __builtin_amdgcn_global_load_lds(
        (__attribute__((address_space(1))) void*)(g),
        (__attribute__((address_space(3))) void*)(l), 16, 0, 0);
}

// tanh-form GELU (max abs err vs exact erf-GELU ~7e-4)
__device__ __forceinline__ float gelu_f(float x) {
    float u = 1.5957691216057308f * (x + 0.044715f * x * x * x);  // 2*sqrt(2/pi)*(...)
    float e = __expf(u);
    float th = 1.0f - 2.0f / (1.0f + e);
    return 0.5f * x * (1.0f + th);
}

// ---------------- fused weight converts ----------------
struct ConvArgs {
    const float* src[19];
    bf16* dst[19];
    int n[19];
    int bstart[20];
};
__global__ __launch_bounds__(256) void convert_many(ConvArgs a) {
    int blk = blockIdx.x;
    int s = 0;
    while (blk >= a.bstart[s + 1]) s++;
    const float* src = a.src[s];
    bf16* dst = a.dst[s];
    int n = a.n[s];
    int i0 = (blk - a.bstart[s]) * 2048;
#pragma unroll
    for (int e = 0; e < 8; e++) {
        int i = i0 + threadIdx.x + e * 256;
        if (i < n) dst[i] = (bf16)src[i];
    }
}

__global__ void zero_kernel(bf16* dst, int n) {
    int i = blockIdx.x * blockDim.x + threadIdx.x;
    if (i < n) dst[i] = (bf16)0.0f;
}

// ---------------- split-K reduce: out = [gelu](P0+P1+bias) [+resid] ----------------
template<int ACT, int RES, class RT, class OT>
__global__ __launch_bounds__(256) void reduce_kernel(
    const bf16* __restrict__ P0, const bf16* __restrict__ P1,
    const bf16* __restrict__ bias, const RT* __restrict__ resid,
    OT* __restrict__ out, int nmask, int total)
{
    int i = (blockIdx.x * 256 + threadIdx.x) * 8;
    if (i >= total) return;
    bf16x8 p0 = *(const bf16x8*)(P0 + i);
    bf16x8 p1 = *(const bf16x8*)(P1 + i);
    bf16x8 bb = *(const bf16x8*)(bias + (i & nmask));
#pragma unroll
    for (int j = 0; j < 8; j++) {
        float v = (float)p0[j] + (float)p1[j] + (float)bb[j];
        if (ACT) v = gelu_f(v);
        if (RES) v += (float)resid[i + j];
        out[i + j] = (OT)v;
    }
}

// ---------------- fused Wo-reduce + LayerNorm ----------------
// x1 = P0+P1+bo+xres (written out); h2 = LN(x1)*w+b. One row per block.
// In-place safe vs P0/P1 aliasing: each thread writes only elements it read,
// and all P0/P1 reads precede the block barrier while h2 writes follow it.
__global__ __launch_bounds__(256) void reduce_ln_kernel(
    const bf16* __restrict__ P0, const bf16* __restrict__ P1,
    const bf16* __restrict__ bo, const float* __restrict__ xres,
    bf16* __restrict__ x1, const bf16* __restrict__ w,
    const bf16* __restrict__ b, bf16* __restrict__ h2)
{
    const int C = 1024;
    const int row = blockIdx.x;
    const int tid = threadIdx.x;
    const size_t base = (size_t)row * C + tid * 4;
    float v[4];
#pragma unroll
    for (int j = 0; j < 4; j++) {
        v[j] = (float)P0[base + j] + (float)P1[base + j]
             + (float)bo[tid * 4 + j] + xres[base + j];
    }
    bf16* xo = x1 + base;
#pragma unroll
    for (int j = 0; j < 4; j++) xo[j] = (bf16)v[j];
    float q0 = (float)xo[0], q1 = (float)xo[1], q2 = (float)xo[2], q3 = (float)xo[3];
    float s  = q0 + q1 + q2 + q3;
    float sq = q0*q0 + q1*q1 + q2*q2 + q3*q3;
#pragma unroll
    for (int off = 32; off >= 1; off >>= 1) {
        s  += __shfl_xor(s,  off, 64);
        sq += __shfl_xor(sq, off, 64);
    }
    __shared__ float red[8];
    int wave = tid >> 6;
    if ((tid & 63) == 0) { red[wave] = s; red[4 + wave] = sq; }
    __syncthreads();
    float ts = red[0] + red[1] + red[2] + red[3];
    float tq = red[4] + red[5] + red[6] + red[7];
    float mean = ts * (1.0f / C);
    float var  = tq * (1.0f / C) - mean * mean;
    float rstd = rsqrtf(var + 1e-5f);
    bf16* orow = h2 + base;
#pragma unroll
    for (int j = 0; j < 4; j++) {
        float wj = (float)w[tid * 4 + j], bj = (float)b[tid * 4 + j];
        float qj = (j == 0 ? q0 : j == 1 ? q1 : j == 2 ? q2 : q3);
        orow[j] = (bf16)((qj - mean) * rstd * wj + bj);
    }
}

// ---------------- LayerNorm ----------------
template<class XT>
__global__ __launch_bounds__(256) void ln_kernel(
    const XT* __restrict__ X, const bf16* __restrict__ w,
    const bf16* __restrict__ b, bf16* __restrict__ out)
{
    const int C = 1024;
    const int row = blockIdx.x;
    const int tid = threadIdx.x;
    const XT* xr = X + (size_t)row * C;
    float x0 = (float)xr[tid * 4 + 0], x1 = (float)xr[tid * 4 + 1];
    float x2 = (float)xr[tid * 4 + 2], x3 = (float)xr[tid * 4 + 3];
    float s  = x0 + x1 + x2 + x3;
    float sq = x0*x0 + x1*x1 + x2*x2 + x3*x3;
#pragma unroll
    for (int off = 32; off >= 1; off >>= 1) {
        s  += __shfl_xor(s,  off, 64);
        sq += __shfl_xor(sq, off, 64);
    }
    __shared__ float red[8];
    int wave = tid >> 6;
    if ((tid & 63) == 0) { red[wave] = s; red[4 + wave] = sq; }
    __syncthreads();
    float ts = red[0] + red[1] + red[2] + red[3];
    float tq = red[4] + red[5] + red[6] + red[7];
    float mean = ts * (1.0f / C);
    float var  = tq * (1.0f / C) - mean * mean;
    float rstd = rsqrtf(var + 1e-5f);
    float w0 = (float)w[tid*4+0], w1 = (float)w[tid*4+1], w2 = (float)w[tid*4+2], w3 = (float)w[tid*4+3];
    float b0 = (float)b[tid*4+0], b1 = (float)b[tid*4+1], b2 = (float)b[tid*4+2], b3 = (float)b[tid*4+3];
    bf16* orow = out + (size_t)row * C + tid * 4;
    orow[0] = (bf16)((x0 - mean) * rstd * w0 + b0);
    orow[1] = (bf16)((x1 - mean) * rstd * w1 + b1);
    orow[2] = (bf16)((x2 - mean) * rstd * w2 + b2);
    orow[3] = (bf16)((x3 - mean) * rstd * w3 + b3);
}

// shared epilogue element (OMODE 0 normal / 2 qkv-split)
template<int ACT, int OMODE, class RT, class OT>
__device__ __forceinline__ void epi_elem(
    float v, int gm, int gn, int N, float scale,
    const bf16* __restrict__ bias, const RT* __restrict__ resid,
    OT* __restrict__ out, bf16* __restrict__ out_k, bf16* __restrict__ out_v)
{
    if (bias) v += (float)bias[gn];
    if (OMODE == 2) {
        if (gn < 2048) {
            v *= scale;
            if (gn < 1024) v *= 1.4426950408889634f;  // exp2-domain softmax
        }
    } else v *= scale;
    if (ACT == 1) v = gelu_f(v);
    if (OMODE == 2) {
        if (gn < 1024) {
            ((bf16*)out)[(size_t)gm * 1024 + gn] = (bf16)v;            // q
        } else if (gn < 2048) {
            out_k[(size_t)gm * 1024 + (gn - 1024)] = (bf16)v;          // k
        } else {
            int gg = gn - 2048;
            int bb = gm / 1500;
            int ss = gm - bb * 1500;
            int hh = gg >> 6, dd = gg & 63;
            out_v[(((size_t)bb * 16 + hh) * 64 + dd) * 1536 + ss] = (bf16)v;  // v^T
        }
    } else {
        if (resid) v += (float)resid[(size_t)gm * N + gn];
        out[(size_t)gm * N + gn] = (OT)v;
    }
}

// ---------------- GEMM 128x128, BK=64 (single-buffer r1 structure; proven) ----------------
// OMODE 0: normal; 2: fused QKV split; 3: split-K partial (blockIdx.y selects
//          K-half and output buffer). ldK = row stride (full K); K = block's K extent.
template<int ACT, int OMODE, class RT, class OT>
__global__ __launch_bounds__(256) void gemm_kernel(
    const bf16* __restrict__ A, const bf16* __restrict__ W,
    const bf16* __restrict__ bias, const RT* __restrict__ resid,
    OT* __restrict__ out, bf16* __restrict__ out_k, bf16* __restrict__ out_v,
    int M, int N, int K, float scale, int gmT, int gnT, int mQ, int ldK)
{
    const int lin = blockIdx.x;
    const int xcd = lin & 7;
    const int t_  = lin >> 3;
    const int mt_ = (xcd & 3) + 4 * (t_ % mQ);
    const int nt_ = (xcd >> 2) + 2 * (t_ / mQ);
    if (mt_ >= gmT || nt_ >= gnT) return;
    const int m0 = mt_ * 128;
    const int n0 = nt_ * 128;
    const int ksp = (OMODE == 3) ? blockIdx.y : 0;
    const size_t ko = (size_t)ksp * K;

    __shared__ __align__(16) bf16 As[16 * 512];
    __shared__ __align__(16) bf16 Bs[16 * 512];
    const int tid = threadIdx.x;
    const int wave = tid >> 6, lane = tid & 63;
    const int lane15 = lane & 15, quad = lane >> 4;
    const int wm0 = (wave >> 1) * 64;
    const int wn0 = (wave & 1) * 64;
    f32x4 acc[4][4] = {};

    int ra0 = m0 + (2 * wave)     * 16 + lane15; if (ra0 > M - 1) ra0 = M - 1;
    int ra1 = m0 + (2 * wave + 1) * 16 + lane15; if (ra1 > M - 1) ra1 = M - 1;
    const int rb0 = n0 + (2 * wave)     * 16 + lane15;
    const int rb1 = n0 + (2 * wave + 1) * 16 + lane15;
    const bf16* a0 = A + (size_t)ra0 * ldK + ko + quad * 8;
    const bf16* a1 = A + (size_t)ra1 * ldK + ko + quad * 8;
    const bf16* w0 = W + (size_t)rb0 * ldK + ko + quad * 8;
    const bf16* w1 = W + (size_t)rb1 * ldK + ko + quad * 8;

    for (int k0 = 0; k0 < K; k0 += 64) {
#pragma unroll
        for (int kk = 0; kk < 2; kk++) {
            load16_lds(a0 + k0 + kk * 32, &As[((2 * wave)     * 2 + kk) * 512]);
            load16_lds(a1 + k0 + kk * 32, &As[((2 * wave + 1) * 2 + kk) * 512]);
            load16_lds(w0 + k0 + kk * 32, &Bs[((2 * wave)     * 2 + kk) * 512]);
            load16_lds(w1 + k0 + kk * 32, &Bs[((2 * wave + 1) * 2 + kk) * 512]);
        }
        __syncthreads();
#pragma unroll
        for (int kk = 0; kk < 2; kk++) {
            bf16x8 af[4], bfr[4];
#pragma unroll
            for (int tt = 0; tt < 4; tt++) {
                af[tt]  = *(const bf16x8*)(&As[(((wm0 >> 4) + tt) * 2 + kk) * 512 + lane * 8]);
                bfr[tt] = *(const bf16x8*)(&Bs[(((wn0 >> 4) + tt) * 2 + kk) * 512 + lane * 8]);
            }
#pragma unroll
            for (int mt = 0; mt < 4; mt++)
#pragma unroll
                for (int nt = 0; nt < 4; nt++)
                    acc[mt][nt] = __builtin_amdgcn_mfma_f32_16x16x32_bf16(
                        af[mt], bfr[nt], acc[mt][nt], 0, 0, 0);
        }
        __syncthreads();
    }

#pragma unroll
    for (int mt = 0; mt < 4; mt++) {
#pragma unroll
        for (int r = 0; r < 4; r++) {
            int gm = m0 + wm0 + mt * 16 + quad * 4 + r;
            if (gm >= M) continue;
#pragma unroll
            for (int nt = 0; nt < 4; nt++) {
                int gn = n0 + wn0 + nt * 16 + lane15;
                if (OMODE == 3) {
                    bf16* po = ksp ? out_k : (bf16*)out;
                    po[(size_t)gm * N + gn] = (bf16)acc[mt][nt][r];
                    continue;
                }
                epi_elem<ACT, OMODE, RT, OT>(acc[mt][nt][r], gm, gn, N, scale,
                                             bias, resid, out, out_k, out_v);
            }
        }
    }
}

// ---------------- GEMM 256x128 wide-tile (8 waves, BK=64, single-buffer) ----------------
// Staged bytes per output: (256+128)*K*2B per 32768 outputs = 1.5x better than 128^2.
// Identical staging/read/epilogue formulas to gemm_kernel; only the wave grid
// (4Mx2N) and B-staging (1 row-group per wave) differ. LDS 48 KB -> 3 blocks/CU.
// OMODE 0 (normal) or 2 (fused QKV split epilogue).
template<int ACT, int OMODE, class OT>
__global__ __launch_bounds__(512) void gemm_wide_kernel(
    const bf16* __restrict__ A, const bf16* __restrict__ W,
    const bf16* __restrict__ bias, OT* __restrict__ out,
    bf16* __restrict__ out_k, bf16* __restrict__ out_v,
    int M, int N, int K, float scale, int gmT, int gnT, int mQ, int ldK)
{
    const int lin = blockIdx.x;
    const int xcd = lin & 7;
    const int t_  = lin >> 3;
    const int mt_ = (xcd & 3) + 4 * (t_ % mQ);
    const int nt_ = (xcd >> 2) + 2 * (t_ / mQ);
    if (mt_ >= gmT || nt_ >= gnT) return;
    const int m0 = mt_ * 256;
    const int n0 = nt_ * 128;

    __shared__ __align__(16) bf16 As[32 * 512];   // 16 row-groups x 2 kk
    __shared__ __align__(16) bf16 Bs[16 * 512];   // 8 row-groups x 2 kk
    const int tid = threadIdx.x;
    const int wave = tid >> 6, lane = tid & 63;
    const int lane15 = lane & 15, quad = lane >> 4;
    const int wm0 = (wave >> 1) * 64;   // 4 wave-rows: 0,64,128,192
    const int wn0 = (wave & 1) * 64;    // 2 wave-cols: 0,64
    f32x4 acc[4][4] = {};

    int ra0 = m0 + (2 * wave)     * 16 + lane15; if (ra0 > M - 1) ra0 = M - 1;
    int ra1 = m0 + (2 * wave + 1) * 16 + lane15; if (ra1 > M - 1) ra1 = M - 1;
    const int rb = n0 + wave * 16 + lane15;      // 8 waves cover 128 B-rows
    const bf16* a0 = A + (size_t)ra0 * ldK + quad * 8;
    const bf16* a1 = A + (size_t)ra1 * ldK + quad * 8;
    const bf16* w0 = W + (size_t)rb * ldK + quad * 8;

    for (int k0 = 0; k0 < K; k0 += 64) {
#pragma unroll
        for (int kk = 0; kk < 2; kk++) {
            load16_lds(a0 + k0 + kk * 32, &As[((2 * wave)     * 2 + kk) * 512]);
            load16_lds(a1 + k0 + kk * 32, &As[((2 * wave + 1) * 2 + kk) * 512]);
            load16_lds(w0 + k0 + kk * 32, &Bs[(wave * 2 + kk) * 512]);
        }
        __syncthreads();
#pragma unroll
        for (int kk = 0; kk < 2; kk++) {
            bf16x8 af[4], bfr[4];
#pragma unroll
            for (int tt = 0; tt < 4; tt++) {
                af[tt]  = *(const bf16x8*)(&As[(((wm0 >> 4) + tt) * 2 + kk) * 512 + lane * 8]);
                bfr[tt] = *(const bf16x8*)(&Bs[(((wn0 >> 4) + tt) * 2 + kk) * 512 + lane * 8]);
            }
#pragma unroll
            for (int mt = 0; mt < 4; mt++)
#pragma unroll
                for (int nt = 0; nt < 4; nt++)
                    acc[mt][nt] = __builtin_amdgcn_mfma_f32_16x16x32_bf16(
                        af[mt], bfr[nt], acc[mt][nt], 0, 0, 0);
        }
        __syncthreads();
    }

#pragma unroll
    for (int mt = 0; mt < 4; mt++) {
#pragma unroll
        for (int r = 0; r < 4; r++) {
            int gm = m0 + wm0 + mt * 16 + quad * 4 + r;
            if (gm >= M) continue;
#pragma unroll
            for (int nt = 0; nt < 4; nt++) {
                int gn = n0 + wn0 + nt * 16 + lane15;
                epi_elem<ACT, OMODE, bf16, OT>(acc[mt][nt][r], gm, gn, N, scale,
                                               bias, (const bf16*)nullptr,
                                               out, out_k, out_v);
            }
        }
    }
}

// ---------------- Flash attention (2-phase double-buffered K/V) ----------------
__global__ __launch_bounds__(256) void flash_attn_kernel(
    const bf16* __restrict__ Q, const bf16* __restrict__ Km,
    const bf16* __restrict__ Vt, bf16* __restrict__ O)
{
    const int S = 1500, C = 1024, SP = 1536;
    const int LDP = 72;
    __shared__ __align__(16) bf16 Ks[2][8 * 512];
    __shared__ __align__(16) bf16 Vs[2][8 * 512];
    __shared__ __align__(16) bf16 Ps[4 * 16 * LDP];
    const int tid = threadIdx.x;
    const int wave = tid >> 6, lane = tid & 63;
    const int lane15 = lane & 15, quad = lane >> 4;
    const int bh = blockIdx.y;
    const int q0 = blockIdx.x * 64;
    const size_t headoff = (size_t)(bh >> 4) * S * C + (size_t)(bh & 15) * 64;
    const size_t vtoff   = (size_t)bh * 64 * SP;

    bf16x8 qf[2];
    int qr = q0 + wave * 16 + lane15; if (qr > S - 1) qr = S - 1;
    qf[0] = *(const bf16x8*)(Q + headoff + (size_t)qr * C + quad * 8);
    qf[1] = *(const bf16x8*)(Q + headoff + (size_t)qr * C + 32 + quad * 8);

    const bf16* vbase = Vt + vtoff + (size_t)(wave * 16 + lane15) * SP + quad * 8;

    auto stageKV = [&](int buf, int kt) {
        const int j0 = kt * 64;
        int kr = j0 + wave * 16 + lane15; if (kr > S - 1) kr = S - 1;
        const bf16* kbase = Km + headoff + (size_t)kr * C + quad * 8;
#pragma unroll
        for (int kk = 0; kk < 2; kk++) {
            load16_lds(kbase + kk * 32,      &Ks[buf][(wave * 2 + kk) * 512]);
            load16_lds(vbase + j0 + kk * 32, &Vs[buf][(wave * 2 + kk) * 512]);
        }
    };

    float m_run[4], l_part[4];
    f32x4 o_acc[4] = {};
#pragma unroll
    for (int r = 0; r < 4; r++) { m_run[r] = 4.0f; l_part[r] = 0.0f; }

    stageKV(0, 0);
    asm volatile("s_waitcnt vmcnt(0)" ::: "memory");
    __builtin_amdgcn_s_barrier();
    __builtin_amdgcn_sched_barrier(0);

    int cur = 0;
    for (int kt = 0; kt < 24; kt++) {
        if (kt + 1 < 24) stageKV(cur ^ 1, kt + 1);
        const int j0 = kt * 64;

        f32x4 s[4] = {};
#pragma unroll
        for (int kk = 0; kk < 2; kk++) {
#pragma unroll
            for (int nt = 0; nt < 4; nt++) {
                bf16x8 kf = *(const bf16x8*)(&Ks[cur][(nt * 2 + kk) * 512 + lane * 8]);
                s[nt] = __builtin_amdgcn_mfma_f32_16x16x32_bf16(qf[kk], kf, s[nt], 0, 0, 0);
            }
        }
        if (kt == 23) {
#pragma unroll
            for (int nt = 0; nt < 4; nt++) {
                if (j0 + nt * 16 + lane15 >= S) {
#pragma unroll
                    for (int r = 0; r < 4; r++) s[nt][r] = -1e30f;
                }
            }
        }

        float tm[4];
#pragma unroll
        for (int r = 0; r < 4; r++)
            tm[r] = fmaxf(fmaxf(s[0][r], s[1][r]), fmaxf(s[2][r], s[3][r]));
        bool rec = (tm[0] > m_run[0]) | (tm[1] > m_run[1]) |
                   (tm[2] > m_run[2]) | (tm[3] > m_run[3]);
        if (__any(rec)) {
#pragma unroll
            for (int r = 0; r < 4; r++) {
                float rm = tm[r];
#pragma unroll
                for (int off = 1; off < 16; off <<= 1) rm = fmaxf(rm, __shfl_xor(rm, off, 64));
                float mnew  = fmaxf(m_run[r], rm);
                float alpha = __builtin_amdgcn_exp2f(m_run[r] - mnew);
                m_run[r] = mnew;
                l_part[r] *= alpha;
#pragma unroll
                for (int dt = 0; dt < 4; dt++) o_acc[dt][r] *= alpha;
            }
        }

#pragma unroll
        for (int nt = 0; nt < 4; nt++) {
#pragma unroll
            for (int r = 0; r < 4; r++) {
                float p = __builtin_amdgcn_exp2f(s[nt][r] - m_run[r]);
                l_part[r] += p;
                Ps[wave * 16 * LDP + (quad * 4 + r) * LDP + nt * 16 + lane15] = (bf16)p;
            }
        }
        asm volatile("s_waitcnt lgkmcnt(0)" ::: "memory");
        __builtin_amdgcn_sched_barrier(0);
#pragma unroll
        for (int kk = 0; kk < 2; kk++) {
            bf16x8 pf = *(const bf16x8*)(&Ps[wave * 16 * LDP + lane15 * LDP + kk * 32 + quad * 8]);
#pragma unroll
            for (int dt = 0; dt < 4; dt++) {
                bf16x8 vf = *(const bf16x8*)(&Vs[cur][(dt * 2 + kk) * 512 + lane * 8]);
                o_acc[dt] = __builtin_amdgcn_mfma_f32_16x16x32_bf16(pf, vf, o_acc[dt], 0, 0, 0);
            }
        }
        if (kt + 1 < 24) {
            asm volatile("s_waitcnt vmcnt(0)" ::: "memory");
            __builtin_amdgcn_s_barrier();
            __builtin_amdgcn_sched_barrier(0);
        }
        cur ^= 1;
    }

    float l_inv[4];
#pragma unroll
    for (int r = 0; r < 4; r++) {
        float ls = l_part[r];
#pragma unroll
        for (int off = 1; off < 16; off <<= 1) ls += __shfl_xor(ls, off, 64);
        l_inv[r] = 1.0f / ls;
    }

#pragma unroll
    for (int dt = 0; dt < 4; dt++) {
#pragma unroll
        for (int r = 0; r < 4; r++) {
            int row = q0 + wave * 16 + quad * 4 + r;
            if (row < S) {
                float v = o_acc[dt][r] * l_inv[r];
                O[headoff + (size_t)row * C + dt * 16 + lane15] = (bf16)v;
            }
        }
    }
}

extern "C" void kernel_launch(void* const* d_in, const int* in_sizes, int n_in,
                              void* d_out, int out_size, void* d_ws, size_t ws_size,
                              hipStream_t stream) {
    float* out = (float*)d_out;
    const float* x_f32 = (const float*)d_in[0];
    const int M = 6000, Cc = 1024, F = 4096, Aa = 256;
    const size_t MC = (size_t)M * Cc;
    const size_t VT_ELEMS = (size_t)64 * 64 * 1536;
    bf16* ws = (bf16*)d_ws;

    bf16* h1   = ws;                         // [M,C]
    bf16* kbuf = ws + MC;                    // [M,C]
    bf16* Vt   = ws + 2 * MC;                // [64][64][1536]
    bf16* g    = ws + 2 * MC + VT_ELEMS;     // [M,F]
    bf16* q    = (bf16*)d_out;               // d_out spare half as bf16 scratch
    bf16* wv   = h1;
    bf16* x1   = q;
    bf16* h2   = kbuf;
    bf16* x2   = Vt;
    bf16* aact = kbuf;
    // split-K partial buffers (regions dead at time of use; stream-ordered):
    bf16* P0o  = kbuf;                       // Wo partials: kbuf free (attn done)
    bf16* P1o  = g;                          //              g free (W1 not yet)
    bf16* P0   = kbuf;                       // W2 partials: h2 consumed by W1
    bf16* P1   = h1;                         //              wv consumed by Wo
    bf16* P0d  = h1;                         // Wds partials: P1 consumed
    bf16* P1d  = h1 + (size_t)M * Aa;
    bf16* P0u  = g;                          // Wus partials: g consumed by W2
    bf16* P1u  = g + MC;

    size_t off = 2 * MC + VT_ELEMS + (size_t)M * F;
    bf16* Wqkv = ws + off; off += (size_t)3 * 1024 * 1024;
    bf16* bqkv = ws + off; off += 3072;
    bf16* sWo  = ws + off; off += (size_t)1024 * 1024;
    bf16* sbo  = ws + off; off += 1024;
    bf16* slnw = ws + off; off += 1024;
    bf16* slnb = ws + off; off += 1024;
    bf16* sW1  = ws + off; off += (size_t)4096 * 1024;
    bf16* sb1  = ws + off; off += 4096;
    bf16* sW2  = ws + off; off += (size_t)1024 * 4096;
    bf16* sb2  = ws + off; off += 1024;
    bf16* sln2w = ws + off; off += 1024;
    bf16* sln2b = ws + off; off += 1024;
    bf16* sWds = ws + off; off += (size_t)256 * 1024;
    bf16* sbds = ws + off; off += 256;
    bf16* sWus = ws + off; off += (size_t)1024 * 256;
    bf16* sbus = ws + off; off += 1024;

    ConvArgs ca;
    const int srcidx[19] = {1, 3, 4, 2, 5, 6, 7, 8, 9, 10, 11, 12, 13, 14, 15, 16, 17, 18, 19};
    bf16* dsts[19] = {Wqkv, Wqkv + 1048576, Wqkv + 2097152, bqkv, bqkv + 2048,
                      sWo, sbo, slnw, slnb, sW1, sb1, sW2, sb2, sln2w, sln2b,
                      sWds, sbds, sWus, sbus};
    int bacc = 0;
    for (int i = 0; i < 19; i++) {
        ca.src[i] = (const float*)d_in[srcidx[i]];
        ca.dst[i] = dsts[i];
        ca.n[i] = in_sizes[srcidx[i]];
        ca.bstart[i] = bacc;
        bacc += (ca.n[i] + 2047) / 2048;
    }
    ca.bstart[19] = bacc;

    dim3 blk(256);
    dim3 blk512(512);
    convert_many<<<bacc, blk, 0, stream>>>(ca);
    zero_kernel<<<4, blk, 0, stream>>>(bqkv + 1024, 1024);   // no k-bias

    const float scale = 0.35355339059327373f;  // 64^-0.25
    const int gmT = 47, mQ = 12;               // 128-row tiles
    auto grid_for = [&](int gnT) { int nQ = (gnT + 1) >> 1; return dim3(8 * mQ * nQ); };
    const int gmTw = 24, mQw = 6;              // 256-row tiles (wide kernel)
    auto gridw_for = [&](int gnT) { int nQ = (gnT + 1) >> 1; return dim3(8 * mQw * nQ); };

    ln_kernel<float><<<M, blk, 0, stream>>>(x_f32, slnw, slnb, h1);
    // QKV: 256x128 wide tile with fused q/k/v^T epilogue (0.77x staged bytes)
    gemm_wide_kernel<0, 2, bf16><<<gridw_for(24), blk512, 0, stream>>>(
        h1, Wqkv, bqkv, q, kbuf, Vt, M, 3072, Cc, scale, gmTw, 24, mQw, Cc);
    dim3 ga(24, 64);
    flash_attn_kernel<<<ga, blk, 0, stream>>>(q, kbuf, Vt, wv);

    // Wo: split-K=2, then fused reduce+LN (x1 and h2 in one pass)
    {
        dim3 gr = grid_for(8); gr.y = 2;
        gemm_kernel<0, 3, bf16, bf16><<<gr, blk, 0, stream>>>(
            wv, sWo, nullptr, (const bf16*)nullptr, P0o, P1o, nullptr,
            M, Cc, Cc / 2, 1.0f, gmT, 8, mQ, Cc);
        reduce_ln_kernel<<<M, blk, 0, stream>>>(
            P0o, P1o, sbo, x_f32, x1, sln2w, sln2b, h2);
    }

    // W1: 256x128 wide tile
    gemm_wide_kernel<1, 0, bf16><<<gridw_for(32), blk512, 0, stream>>>(
        h2, sW1, sb1, g, nullptr, nullptr, M, F, Cc, 1.0f, gmTw, 32, mQw, Cc);

    // W2: split-K=2, reduce adds b2 + x1 resid
    {
        dim3 gr = grid_for(8); gr.y = 2;
        gemm_kernel<0, 3, bf16, bf16><<<gr, blk, 0, stream>>>(
            g, sW2, nullptr, (const bf16*)nullptr, P0, P1, nullptr,
            M, Cc, F / 2, 1.0f, gmT, 8, mQ, F);
        reduce_kernel<0, 1, bf16, bf16><<<(M * Cc) / 2048, blk, 0, stream>>>(
            P0, P1, sb2, x1, x2, Cc - 1, M * Cc);
    }

    // adapter down (Wds): split-K=2, gelu-reduce
    {
        dim3 gr = grid_for(2); gr.y = 2;
        gemm_kernel<0, 3, bf16, bf16><<<gr, blk, 0, stream>>>(
            x2, sWds, nullptr, (const bf16*)nullptr, P0d, P1d, nullptr,
            M, Aa, Cc / 2, 1.0f, gmT, 2, mQ, Cc);
        reduce_kernel<1, 0, bf16, bf16><<<(M * Aa) / 2048, blk, 0, stream>>>(
            P0d, P1d, sbds, nullptr, aact, Aa - 1, M * Aa);
    }

    // adapter up (Wus): split-K=2, reduce adds bus + x2, float out
    {
        dim3 gr = grid_for(8); gr.y = 2;
        gemm_kernel<0, 3, bf16, bf16><<<gr, blk, 0, stream>>>(
            aact, sWus, nullptr, (const bf16*)nullptr, P0u, P1u, nullptr,
            M, Cc, Aa / 2, 1.0f, gmT, 8, mQ, Aa);
        reduce_kernel<0, 1, bf16, float><<<(M * Cc) / 2048, blk, 0, stream>>>(
            P0u, P1u, sbus, x2, out, Cc - 1, M * Cc);
    }
}